// Round 2
// baseline (440.862 us; speedup 1.0000x reference)
//
#include <hip/hip_runtime.h>
#include <hip/hip_bf16.h>
#include <stdint.h>
#include <stddef.h>

typedef _Float16 f16;
typedef __attribute__((ext_vector_type(8))) _Float16 f16x8;  // 4 VGPRs (MFMA A/B)
typedef __attribute__((ext_vector_type(4))) float    f32x4;  // MFMA C/D

constexpr int BM = 128, BN = 128, BK = 64;   // for the legacy o-GEMM only

// async global->LDS DMA, 16 B/lane; LDS dest = wave-uniform base + lane*16
#define GLOAD_LDS16(gp, lp)                                        \
    __builtin_amdgcn_global_load_lds(                              \
        (const __attribute__((address_space(1))) unsigned int*)(gp),\
        (__attribute__((address_space(3))) unsigned int*)(lp), 16, 0, 0)

// one phase's MFMA cluster: 16 x mfma_f32_16x16x32_f16 wrapped in setprio (T5)
#define MFMA_TILE(AV, BV)                                                     \
    do {                                                                      \
        __builtin_amdgcn_s_setprio(1);                                        \
        _Pragma("unroll")                                                     \
        for (int mi_ = 0; mi_ < 4; ++mi_)                                     \
            _Pragma("unroll")                                                 \
            for (int ni_ = 0; ni_ < 4; ++ni_)                                 \
                acc[mi_][ni_] = __builtin_amdgcn_mfma_f32_16x16x32_f16(       \
                    (AV)[mi_], (BV)[ni_], acc[mi_][ni_], 0, 0, 0);            \
        __builtin_amdgcn_s_setprio(0);                                        \
    } while (0)

// ===========================================================================
// BK=32 pipelined 2-term GEMM for the causal S product.
// C = (Ah+Al) @ B^T, f16 in / fp32 accum. BM=128, BN=256, BK=32.
// 512 threads = 8 waves (2M x 4N), 64x64 out per wave.
//
// KEY: LDS is only 64 KiB (2buf x [A2 16K | B 16K]) -> 2 blocks/CU, which
// removes the 272-blocks-on-256-CUs second-round quantization (the 16 CUs
// that host 2 blocks interleave them instead of running 2 serial rounds).
//
// Packed LDS layout (128 B lines of 8 x 16 B groups, XOR-swizzled):
//   A2 line r (r=0..127):  logical group g = term*4 + k/8  (term 0=Ah,1=Al)
//                          physical group  = g ^ (r & 7)
//   B  line p (p=0..127):  holds rows 2p (h=0) and 2p+1 (h=1);
//                          g = h*4 + k/8, physical = g ^ (p & 7)
// Staging (global_load_lds writes linearly: thread t -> line t>>3, phys grp
// t&7) fetches the INVERSE-swizzled logical element; the per-lane global
// source address absorbs the swizzle (rule: both-sides-or-neither).
//
// Schedule per K-tile (2 phases, 16 MFMA each):
//   phase A: ds_read ah+bv | stage ALL 4 loads of tile t+1 | bar | lgkm0 |
//            MFMA(ah,bv) | bar
//   phase B: ds_read al    | bar | lgkm0 | MFMA(al,bv) | vmcnt(0) | bar
// The drain at end of phase B waits loads issued a full tile (~1200 cyc)
// earlier -> latency covered; buffer t+1 is then ready for phase A reads.
template <int EPI, bool CAUSAL>
__global__ __launch_bounds__(512, 4) void gemm32_a2(
    const f16* __restrict__ Ah, const f16* __restrict__ Al,
    const f16* __restrict__ B,
    float* __restrict__ Cf, f16* __restrict__ Co, f16* __restrict__ Clo,
    int M, int N, int K)
{
    const int bx = blockIdx.x;
    const int by = blockIdx.y;
    if (CAUSAL && 2 * bx > by) return;

    const int tid   = threadIdx.x;
    const int lane  = tid & 63;
    const int wave  = tid >> 6;   // 0..7
    const int wm    = wave >> 2;  // 0..1  (M)
    const int wn    = wave & 3;   // 0..3  (N)
    const int lrow  = lane & 15;
    const int lquad = lane >> 4;

    __shared__ f16 lds[2][16384];   // 64 KiB total -> 2 blocks/CU

    const int row0 = by * 128;
    const int col0 = bx * 256;

    // half-dead diagonal blocks (even by, 2bx==by): cols >= row0+128 are
    // fully masked by softmax and never read -> skip compute for wn>=2.
    const bool liveN = !CAUSAL || (col0 + wn * 64 <= row0 + 127);

    // staging source map (see header comment)
    const int srA  = tid >> 3;                        // line 0..63 within unit
    const int gl   = (tid & 7) ^ (srA & 7);           // logical group
    const int term = gl >> 2;                         // A: term / B: h
    const int cg   = gl & 3;                          // k-group
    const f16* pA = (term ? Al : Ah) + (size_t)(row0 + srA) * K + cg * 8;
    const f16* pB = B + (size_t)(col0 + 2 * srA + term) * K + cg * 8;
    const size_t uA = (size_t)64 * K;    // A unit-1 row offset
    const size_t uB = (size_t)128 * K;   // B unit-1 row offset
    const int ld0 = wave * 512;          // wave slice inside a 8 KiB unit

    // ds_read fragment offsets (f16 elems; +1024 per mi, +512 per ni)
    const int aoff0 = (wm * 64 + lrow) * 64 + ((lquad ^ (lrow & 7)) * 8);
    const int aoff1 = (wm * 64 + lrow) * 64 + (((4 + lquad) ^ (lrow & 7)) * 8);
    const int boff  = 8192 + (wn * 32 + (lrow >> 1)) * 64 +
                      ((((lrow & 1) * 4 + lquad) ^ ((lrow >> 1) & 7)) * 8);

    f32x4 acc[4][4];
    const f32x4 fz = {0.f, 0.f, 0.f, 0.f};
    #pragma unroll
    for (int i = 0; i < 4; ++i)
        #pragma unroll
        for (int j = 0; j < 4; ++j) acc[i][j] = fz;

    const int nt = K / 32;

    // prologue: stage tile 0 into buffer 0
    GLOAD_LDS16(pA,      &lds[0][ld0]);
    GLOAD_LDS16(pA + uA, &lds[0][4096 + ld0]);
    GLOAD_LDS16(pB,      &lds[0][8192 + ld0]);
    GLOAD_LDS16(pB + uB, &lds[0][12288 + ld0]);
    asm volatile("s_waitcnt vmcnt(0)");
    __builtin_amdgcn_s_barrier();

    for (int t = 0; t < nt; ++t) {
        const f16* bufc = &lds[t & 1][0];
        f16* bufn = &lds[(t + 1) & 1][0];
        const bool stage = (t + 1 < nt);
        const size_t kn = (size_t)(t + 1) * 32;

        f16x8 ah[4], al[4], bv[4];

        // ---------- phase A: Ah term
        if (liveN) {
            #pragma unroll
            for (int mi = 0; mi < 4; ++mi)
                ah[mi] = *(const f16x8*)&bufc[aoff0 + mi * 1024];
            #pragma unroll
            for (int ni = 0; ni < 4; ++ni)
                bv[ni] = *(const f16x8*)&bufc[boff + ni * 512];
        }
        if (stage) {
            GLOAD_LDS16(pA + kn,      &bufn[ld0]);
            GLOAD_LDS16(pA + uA + kn, &bufn[4096 + ld0]);
            GLOAD_LDS16(pB + kn,      &bufn[8192 + ld0]);
            GLOAD_LDS16(pB + uB + kn, &bufn[12288 + ld0]);
        }
        __builtin_amdgcn_s_barrier();
        asm volatile("s_waitcnt lgkmcnt(0)");
        if (liveN) MFMA_TILE(ah, bv);
        __builtin_amdgcn_s_barrier();

        // ---------- phase B: Al term (bv reused)
        if (liveN) {
            #pragma unroll
            for (int mi = 0; mi < 4; ++mi)
                al[mi] = *(const f16x8*)&bufc[aoff1 + mi * 1024];
        }
        __builtin_amdgcn_s_barrier();
        asm volatile("s_waitcnt lgkmcnt(0)");
        if (liveN) MFMA_TILE(al, bv);
        if (stage) asm volatile("s_waitcnt vmcnt(0)");  // tile t+1 landed
        __builtin_amdgcn_s_barrier();
    }

    if (!liveN) return;   // dead diagonal half: S region never read

    // epilogue: D element (row = lquad*4 + r, col = lrow) within 16x16 tiles
    #pragma unroll
    for (int mi = 0; mi < 4; ++mi) {
        #pragma unroll
        for (int ni = 0; ni < 4; ++ni) {
            #pragma unroll
            for (int r = 0; r < 4; ++r) {
                const int row = row0 + wm * 64 + mi * 16 + lquad * 4 + r;
                const int col = col0 + wn * 64 + ni * 16 + lrow;
                const size_t idx = (size_t)row * N + col;
                const float v = acc[mi][ni][r];
                if (EPI == 0) {
                    Cf[idx] = v;
                } else {
                    const f16 h = (f16)v;
                    Co[idx]  = h;
                    Clo[idx] = (f16)(v - (float)h);
                }
            }
        }
    }
}

// ===========================================================================
// Pipelined 2-term GEMM (dense q product): C = (Ah+Al) @ B^T.
// BM=128, BN=256, BK=64, 512 threads, LDS 128 KiB double-buffered.
// 4 phases/K-tile, counted vmcnt (see round-1 ledger in comments).
template <int EPI, bool CAUSAL>
__global__ __launch_bounds__(512, 2) void gemm8_a2(
    const f16* __restrict__ Ah, const f16* __restrict__ Al,
    const f16* __restrict__ B,
    float* __restrict__ Cf, f16* __restrict__ Co, f16* __restrict__ Clo,
    int M, int N, int K)
{
    const int bx = blockIdx.x;
    const int by = blockIdx.y;
    if (CAUSAL && 2 * bx > by) return;

    const int tid   = threadIdx.x;
    const int lane  = tid & 63;
    const int wave  = tid >> 6;   // 0..7
    const int wm    = wave >> 2;  // 0..1  (M)
    const int wn    = wave & 3;   // 0..3  (N)
    const int lrow  = lane & 15;
    const int lquad = lane >> 4;

    __shared__ f16 lds[2][32768];   // 128 KiB total

    const int row0 = by * 128;
    const int col0 = bx * 256;

    const int srow = tid >> 3;                       // 0..63 (row within unit)
    const int scol = ((tid & 7) ^ (srow & 7)) * 8;   // pre-swizzled source col
    const int loff = wave * 512;                     // wave slice inside a unit

    const int g0 = ((lquad)     ^ (lrow & 7)) * 8;   // swizzled group, kk=0
    const int g1 = ((4 + lquad) ^ (lrow & 7)) * 8;   // swizzled group, kk=1

    const int arow = (wm * 64 + lrow) * 64;           // A frag base (elems)
    const int brow = (wn * 64 + lrow) * 64 + 16384;   // B frag base (elems)

    const f16* gAh = Ah + (size_t)(row0 + srow) * K + scol;
    const f16* gAl = Al + (size_t)(row0 + srow) * K + scol;
    const f16* gB  = B  + (size_t)(col0 + srow) * K + scol;
    const size_t r64 = (size_t)64 * K;

    f32x4 acc[4][4];
    const f32x4 fz = {0.f, 0.f, 0.f, 0.f};
    #pragma unroll
    for (int i = 0; i < 4; ++i)
        #pragma unroll
        for (int j = 0; j < 4; ++j) acc[i][j] = fz;

    const int nt = K / 64;

    // prologue: stage tile 0 into buffer 0
    #pragma unroll
    for (int u = 0; u < 4; ++u)
        GLOAD_LDS16(gB + u * r64, &lds[0][16384 + u * 4096 + loff]);
    #pragma unroll
    for (int u = 0; u < 2; ++u)
        GLOAD_LDS16(gAh + u * r64, &lds[0][u * 4096 + loff]);
    #pragma unroll
    for (int u = 0; u < 2; ++u)
        GLOAD_LDS16(gAl + u * r64, &lds[0][8192 + u * 4096 + loff]);
    asm volatile("s_waitcnt vmcnt(2)");   // B+Ah landed; Al(0) may fly
    __builtin_amdgcn_s_barrier();

    auto tile_body = [&](int t, bool stage) {
        const int cur = t & 1;
        const size_t kn = (size_t)(t + 1) * 64;
        const f16* bufc = &lds[cur][0];
        f16* bufn = &lds[cur ^ 1][0];

        f16x8 av[4], bv0[4], bv1[4];

        // ---------- phase A: Ah x kk0
        #pragma unroll
        for (int mi = 0; mi < 4; ++mi)
            av[mi] = *(const f16x8*)&bufc[arow + mi * 1024 + g0];
        #pragma unroll
        for (int ni = 0; ni < 4; ++ni)
            bv0[ni] = *(const f16x8*)&bufc[brow + ni * 1024 + g0];
        if (stage) {
            GLOAD_LDS16(gB + kn,       &bufn[16384 + loff]);
            GLOAD_LDS16(gB + r64 + kn, &bufn[16384 + 4096 + loff]);
        }
        __builtin_amdgcn_s_barrier();
        asm volatile("s_waitcnt lgkmcnt(0)");
        MFMA_TILE(av, bv0);
        __builtin_amdgcn_s_barrier();

        // ---------- phase B: Ah x kk1
        #pragma unroll
        for (int mi = 0; mi < 4; ++mi)
            av[mi] = *(const f16x8*)&bufc[arow + mi * 1024 + g1];
        #pragma unroll
        for (int ni = 0; ni < 4; ++ni)
            bv1[ni] = *(const f16x8*)&bufc[brow + ni * 1024 + g1];
        if (stage) {
            GLOAD_LDS16(gB + 2 * r64 + kn, &bufn[16384 +  8192 + loff]);
            GLOAD_LDS16(gB + 3 * r64 + kn, &bufn[16384 + 12288 + loff]);
            asm volatile("s_waitcnt vmcnt(4)");   // drain Al(t)
        } else {
            asm volatile("s_waitcnt vmcnt(0)");   // last tile: drain Al(t)
        }
        __builtin_amdgcn_s_barrier();
        asm volatile("s_waitcnt lgkmcnt(0)");
        MFMA_TILE(av, bv1);
        __builtin_amdgcn_s_barrier();

        // ---------- phase C: Al x kk0
        #pragma unroll
        for (int mi = 0; mi < 4; ++mi)
            av[mi] = *(const f16x8*)&bufc[8192 + arow + mi * 1024 + g0];
        if (stage) {
            GLOAD_LDS16(gAh + kn,       &bufn[loff]);
            GLOAD_LDS16(gAh + r64 + kn, &bufn[4096 + loff]);
        }
        __builtin_amdgcn_s_barrier();
        asm volatile("s_waitcnt lgkmcnt(0)");
        MFMA_TILE(av, bv0);
        __builtin_amdgcn_s_barrier();

        // ---------- phase D: Al x kk1
        #pragma unroll
        for (int mi = 0; mi < 4; ++mi)
            av[mi] = *(const f16x8*)&bufc[8192 + arow + mi * 1024 + g1];
        if (stage) {
            GLOAD_LDS16(gAl + kn,       &bufn[ 8192 + loff]);
            GLOAD_LDS16(gAl + r64 + kn, &bufn[12288 + loff]);
        }
        asm volatile("s_waitcnt vmcnt(2)");   // drain B(t+1)+Ah(t+1)
        __builtin_amdgcn_s_barrier();
        asm volatile("s_waitcnt lgkmcnt(0)");
        MFMA_TILE(av, bv1);
        __builtin_amdgcn_s_barrier();
    };

    for (int t = 0; t < nt - 1; ++t) tile_body(t, true);
    tile_body(nt - 1, false);

    // epilogue
    #pragma unroll
    for (int mi = 0; mi < 4; ++mi) {
        #pragma unroll
        for (int ni = 0; ni < 4; ++ni) {
            #pragma unroll
            for (int r = 0; r < 4; ++r) {
                const int row = row0 + wm * 64 + mi * 16 + lquad * 4 + r;
                const int col = col0 + wn * 64 + ni * 16 + lrow;
                const size_t idx = (size_t)row * N + col;
                const float v = acc[mi][ni][r];
                if (EPI == 0) {
                    Cf[idx] = v;
                } else {
                    const f16 h = (f16)v;
                    Co[idx]  = h;
                    Clo[idx] = (f16)(v - (float)h);
                }
            }
        }
    }
}

// ===========================================================================
// Pipelined single-term GEMM: C = A @ B^T, TRIPLE-buffered LDS (144 KiB).
// 2 phases/K-tile, 16 MFMA each; staging 2 tiles ahead; vmcnt(6) steady.
template <int EPI>
__global__ __launch_bounds__(512, 2) void gemm8_1t(
    const f16* __restrict__ A, const f16* __restrict__ B,
    float* __restrict__ Cf, f16* __restrict__ Co,
    int M, int N, int K)
{
    const int bx = blockIdx.x;
    const int by = blockIdx.y;

    const int tid   = threadIdx.x;
    const int lane  = tid & 63;
    const int wave  = tid >> 6;
    const int wm    = wave >> 2;
    const int wn    = wave & 3;
    const int lrow  = lane & 15;
    const int lquad = lane >> 4;

    __shared__ f16 lds[3][24576];   // 144 KiB total

    const int row0 = by * 128;
    const int col0 = bx * 256;

    const int srow = tid >> 3;
    const int scol = ((tid & 7) ^ (srow & 7)) * 8;
    const int loff = wave * 512;
    const int g0 = ((lquad)     ^ (lrow & 7)) * 8;
    const int g1 = ((4 + lquad) ^ (lrow & 7)) * 8;
    const int arow = (wm * 64 + lrow) * 64;
    const int brow = (wn * 64 + lrow) * 64 + 8192;

    const f16* gA = A + (size_t)(row0 + srow) * K + scol;
    const f16* gB = B + (size_t)(col0 + srow) * K + scol;
    const size_t r64 = (size_t)64 * K;

    f32x4 acc[4][4];
    const f32x4 fz = {0.f, 0.f, 0.f, 0.f};
    #pragma unroll
    for (int i = 0; i < 4; ++i)
        #pragma unroll
        for (int j = 0; j < 4; ++j) acc[i][j] = fz;

    const int nt = K / 64;

    // prologue: stage tiles 0 and 1 (order per tile: B0 B1 B2 B3 A0 A1)
    #pragma unroll
    for (int tt = 0; tt < 2; ++tt) {
        const size_t kk = (size_t)tt * 64;
        #pragma unroll
        for (int u = 0; u < 4; ++u)
            GLOAD_LDS16(gB + u * r64 + kk, &lds[tt][8192 + u * 4096 + loff]);
        #pragma unroll
        for (int u = 0; u < 2; ++u)
            GLOAD_LDS16(gA + u * r64 + kk, &lds[tt][u * 4096 + loff]);
    }
    asm volatile("s_waitcnt vmcnt(6)");   // tile 0 landed; tile 1 may fly
    __builtin_amdgcn_s_barrier();

    int cur = 0;
    for (int t = 0; t < nt; ++t) {
        const int nb = (cur >= 1) ? (cur - 1) : (cur + 2);  // (t+2) % 3
        const bool stage2 = (t + 2 < nt);
        const size_t kn = (size_t)(t + 2) * 64;
        const f16* bufc = &lds[cur][0];
        f16* bufn = &lds[nb][0];

        f16x8 av[4], bv[4];

        // ---------- phase A: kk0
        #pragma unroll
        for (int mi = 0; mi < 4; ++mi)
            av[mi] = *(const f16x8*)&bufc[arow + mi * 1024 + g0];
        #pragma unroll
        for (int ni = 0; ni < 4; ++ni)
            bv[ni] = *(const f16x8*)&bufc[brow + ni * 1024 + g0];
        if (stage2) {
            GLOAD_LDS16(gB + kn,           &bufn[8192 + loff]);
            GLOAD_LDS16(gB + r64 + kn,     &bufn[8192 + 4096 + loff]);
            GLOAD_LDS16(gB + 2 * r64 + kn, &bufn[8192 + 8192 + loff]);
        }
        __builtin_amdgcn_s_barrier();
        asm volatile("s_waitcnt lgkmcnt(0)");
        MFMA_TILE(av, bv);
        __builtin_amdgcn_s_barrier();

        // ---------- phase B: kk1
        #pragma unroll
        for (int mi = 0; mi < 4; ++mi)
            av[mi] = *(const f16x8*)&bufc[arow + mi * 1024 + g1];
        #pragma unroll
        for (int ni = 0; ni < 4; ++ni)
            bv[ni] = *(const f16x8*)&bufc[brow + ni * 1024 + g1];
        if (stage2) {
            GLOAD_LDS16(gB + 3 * r64 + kn, &bufn[8192 + 12288 + loff]);
            GLOAD_LDS16(gA + kn,           &bufn[loff]);
            GLOAD_LDS16(gA + r64 + kn,     &bufn[4096 + loff]);
            asm volatile("s_waitcnt vmcnt(6)");   // drain tile t+1
        } else {
            asm volatile("s_waitcnt vmcnt(0)");   // pipeline tail drain
        }
        __builtin_amdgcn_s_barrier();
        asm volatile("s_waitcnt lgkmcnt(0)");
        MFMA_TILE(av, bv);
        __builtin_amdgcn_s_barrier();

        cur = (cur == 2) ? 0 : cur + 1;
    }

    #pragma unroll
    for (int mi = 0; mi < 4; ++mi) {
        #pragma unroll
        for (int ni = 0; ni < 4; ++ni) {
            #pragma unroll
            for (int r = 0; r < 4; ++r) {
                const int row = row0 + wm * 64 + mi * 16 + lquad * 4 + r;
                const int col = col0 + wn * 64 + ni * 16 + lrow;
                const size_t idx = (size_t)row * N + col;
                const float v = acc[mi][ni][r];
                if (EPI == 0) Cf[idx] = v;
                else          Co[idx] = (f16)v;
            }
        }
    }
}

// ===========================================================================
// Legacy 128x128 GEMM kept for the K-causal o = P @ xT^T product (triangular
// K; 4-5 blocks/CU + heavy-first order balance it naturally).
template <int EPI, bool KCAUSAL>
__global__ __launch_bounds__(256) void gemm_plain(
    const f16* __restrict__ A, const f16* __restrict__ B,
    float* __restrict__ Cf, f16* __restrict__ Co,
    int M, int N, int K)
{
    const int bx = blockIdx.x;
    const int by = KCAUSAL ? (gridDim.y - 1 - blockIdx.y) : blockIdx.y;

    const int tid   = threadIdx.x;
    const int lane  = tid & 63;
    const int wave  = tid >> 6;
    const int wm    = wave >> 1;
    const int wn    = wave & 1;
    const int lrow  = lane & 15;
    const int lquad = lane >> 4;

    __shared__ f16 sA[BM * BK];   // 16 KB each, 32 KB total
    __shared__ f16 sB[BN * BK];

    const int row0 = by * BM;
    const int col0 = bx * BN;

    const int srow = tid >> 3;
    const int scol = (((tid & 7) ^ ((tid >> 3) & 7))) * 8;
    const int lbase = wave * 512;

    f32x4 acc[4][4];
    const f32x4 fzero = {0.f, 0.f, 0.f, 0.f};
    #pragma unroll
    for (int i = 0; i < 4; ++i)
        #pragma unroll
        for (int j = 0; j < 4; ++j) acc[i][j] = fzero;

    const int Keff = KCAUSAL ? (by + 1) * BM : K;

    for (int k0 = 0; k0 < Keff; k0 += BK) {
        __syncthreads();
        #pragma unroll
        for (int r = 0; r < 4; ++r) {
            const int trow = srow + 32 * r;
            GLOAD_LDS16(&A[(size_t)(row0 + trow) * K + k0 + scol], &sA[lbase + r * 2048]);
            GLOAD_LDS16(&B[(size_t)(col0 + trow) * K + k0 + scol], &sB[lbase + r * 2048]);
        }
        __syncthreads();

        #pragma unroll
        for (int kk = 0; kk < 2; ++kk) {
            const int grpA = ((kk * 4 + lquad) ^ (lrow & 7)) * 8;
            f16x8 av[4], bv[4];
            #pragma unroll
            for (int mi = 0; mi < 4; ++mi)
                av[mi] = *reinterpret_cast<const f16x8*>(
                    &sA[(wm * 64 + mi * 16 + lrow) * BK + grpA]);
            #pragma unroll
            for (int ni = 0; ni < 4; ++ni)
                bv[ni] = *reinterpret_cast<const f16x8*>(
                    &sB[(wn * 64 + ni * 16 + lrow) * BK + grpA]);

            #pragma unroll
            for (int mi = 0; mi < 4; ++mi)
                #pragma unroll
                for (int ni = 0; ni < 4; ++ni)
                    acc[mi][ni] = __builtin_amdgcn_mfma_f32_16x16x32_f16(
                        av[mi], bv[ni], acc[mi][ni], 0, 0, 0);
        }
    }

    #pragma unroll
    for (int mi = 0; mi < 4; ++mi) {
        #pragma unroll
        for (int ni = 0; ni < 4; ++ni) {
            #pragma unroll
            for (int r = 0; r < 4; ++r) {
                const int row = row0 + wm * 64 + mi * 16 + lquad * 4 + r;
                const int col = col0 + wn * 64 + ni * 16 + lrow;
                const size_t idx = (size_t)row * N + col;
                const float v = acc[mi][ni][r];
                if (EPI == 0) Cf[idx] = v;
                else          Co[idx] = (f16)v;
            }
        }
    }
}

// fp32 -> f16 hi (+ optional lo residual), 4 elems/thread
__global__ __launch_bounds__(256) void split_f32_f16(
    const float* __restrict__ in, f16* __restrict__ hi, f16* __restrict__ lo,
    size_t nelem)
{
    const size_t i = ((size_t)blockIdx.x * 256 + threadIdx.x) * 4;
    if (i >= nelem) return;
    const float4 v = *reinterpret_cast<const float4*>(in + i);
    union { f16 h[4]; ushort4 u; } H, L;
    H.h[0] = (f16)v.x; H.h[1] = (f16)v.y; H.h[2] = (f16)v.z; H.h[3] = (f16)v.w;
    *reinterpret_cast<ushort4*>(hi + i) = H.u;
    if (lo) {
        L.h[0] = (f16)(v.x - (float)H.h[0]);
        L.h[1] = (f16)(v.y - (float)H.h[1]);
        L.h[2] = (f16)(v.z - (float)H.h[2]);
        L.h[3] = (f16)(v.w - (float)H.h[3]);
        *reinterpret_cast<ushort4*>(lo + i) = L.u;
    }
}

// row-wise causal softmax, single global pass (row cached in LDS),
// online max+sum; zero-pads P to the 128 boundary.
__global__ __launch_bounds__(256) void softmax_rows(
    const float* __restrict__ S, f16* __restrict__ P, int n)
{
    const int row = blockIdx.x;
    const int len = row + 1;
    const int padlen = ((row >> 7) + 1) << 7;
    const float* srow = S + (size_t)row * n;
    f16* prow = P + (size_t)row * n;
    const int tid = threadIdx.x;
    const int lane = tid & 63, wave = tid >> 6;
    __shared__ float rowbuf[4096];   // 16 KB row cache (n <= 4096)
    __shared__ float redm[4], reds[4];

    float m = -3.0e38f, s = 0.f;
    for (int j = tid; j < len; j += 256) {
        const float v = srow[j];
        rowbuf[j] = v;
        const float mn = fmaxf(m, v);
        s = s * __expf(m - mn) + __expf(v - mn);
        m = mn;
    }
    #pragma unroll
    for (int off = 32; off; off >>= 1) {
        const float mo = __shfl_xor(m, off, 64);
        const float so = __shfl_xor(s, off, 64);
        const float mn = fmaxf(m, mo);
        s = s * __expf(m - mn) + so * __expf(mo - mn);
        m = mn;
    }
    if (lane == 0) { redm[wave] = m; reds[wave] = s; }
    __syncthreads();
    float M = redm[0], Sm = reds[0];
    #pragma unroll
    for (int w = 1; w < 4; ++w) {
        const float mn = fmaxf(M, redm[w]);
        Sm = Sm * __expf(M - mn) + reds[w] * __expf(redm[w] - mn);
        M = mn;
    }
    const float inv = 1.0f / Sm;

    const f16 z = (f16)0.0f;
    for (int j = tid; j < padlen; j += 256)
        prow[j] = (j < len) ? (f16)(__expf(rowbuf[j] - M) * inv) : z;
}

// out[c*rows + r] = (f16)in[r*cols + c]   (fp32 in, f16 out)
__global__ __launch_bounds__(256) void transpose_f32_f16(
    const float* __restrict__ in, f16* __restrict__ out, int rows, int cols)
{
    __shared__ float tile[32][33];
    const int bx = blockIdx.x;
    const int by = blockIdx.y;
    const int tx = threadIdx.x & 31;
    const int ty = threadIdx.x >> 5;
    #pragma unroll
    for (int r = 0; r < 4; ++r)
        tile[ty + 8 * r][tx] = in[(size_t)(by * 32 + ty + 8 * r) * cols + bx * 32 + tx];
    __syncthreads();
    #pragma unroll
    for (int r = 0; r < 4; ++r)
        out[(size_t)(bx * 32 + ty + 8 * r) * rows + by * 32 + tx] =
            (f16)tile[tx][ty + 8 * r];
}

extern "C" void kernel_launch(void* const* d_in, const int* in_sizes, int n_in,
                              void* d_out, int out_size, void* d_ws, size_t ws_size,
                              hipStream_t stream)
{
    const int n = 4096, d = 2048;
    const float* x   = (const float*)d_in[0];
    const float* Wqk = (const float*)d_in[1];
    const float* Wov = (const float*)d_in[2];
    float* out = (float*)d_out;

    char* ws = (char*)d_ws;
    const size_t MB = 1 << 20;
    f16*   xh   = (f16*)  (ws);             // 16 MB  (n x d)
    f16*   xl   = (f16*)  (ws + 16 * MB);   // 16 MB  (dead after q GEMM)
    f16*   Wh   = (f16*)  (ws + 32 * MB);   //  8 MB  (d x d, dead after q GEMM)
    f16*   Wovh = (f16*)  (ws + 40 * MB);   //  8 MB  (live to end)
    f16*   xTh  = (f16*)  (ws + 48 * MB);   // 16 MB  (d x n, live to o GEMM)
    f16*   qh   = (f16*)  (ws + 64 * MB);   // 16 MB  (dead after S GEMM)
    f16*   ql   = (f16*)  (ws + 80 * MB);   // 16 MB  (dead after S GEMM)
    float* S    = (float*)(ws + 96 * MB);   // 64 MB  (n x n)  -> peak 160 MB
    f16*   P    = (f16*)  (ws);             // 32 MB  (n x n), over xh+xl (dead)
    f16*   o    = (f16*)  (ws + 64 * MB);   // 16 MB  (n x d), over qh (dead)

    const dim3 blk(256);
    const dim3 blk8(512);

    // fp32 -> f16 conversions
    split_f32_f16<<<dim3((n * d) / (256 * 4)), blk, 0, stream>>>(x,   xh, xl, (size_t)n * d);
    split_f32_f16<<<dim3((d * d) / (256 * 4)), blk, 0, stream>>>(Wqk, Wh, nullptr, (size_t)d * d);
    split_f32_f16<<<dim3((d * d) / (256 * 4)), blk, 0, stream>>>(Wov, Wovh, nullptr, (size_t)d * d);
    transpose_f32_f16<<<dim3(d / 32, n / 32), blk, 0, stream>>>(x, xTh, n, d);

    // q = (xh+xl) @ Wh^T, pipelined 2-term, output split f16 hi/lo
    gemm8_a2<1, false><<<dim3(d / 256, n / 128), blk8, 0, stream>>>(
        xh, xl, Wh, nullptr, qh, ql, n, d, d);

    // S = (qh+ql) @ xh^T, causal blocks, fp32 store; BK=32 / 64 KiB LDS
    // variant -> 2 blocks/CU kills the 272-on-256 second-round quantization
    gemm32_a2<0, true><<<dim3(n / 256, n / 128), blk8, 0, stream>>>(
        qh, ql, xh, S, nullptr, nullptr, n, n, d);

    // P = causal row softmax(S), f16, zero-padded to 128 boundary
    softmax_rows<<<dim3(n), blk, 0, stream>>>(S, P, n);

    // o = P @ xTh^T  (K limited causally per row-block), f16
    gemm_plain<2, true><<<dim3(d / BN, n / BM), blk, 0, stream>>>(
        P, xTh, nullptr, o, n, d, n);

    // out = o @ Wovh^T, pipelined single-term, fp32 store to d_out
    gemm8_1t<0><<<dim3(d / 256, n / 128), blk8, 0, stream>>>(
        o, Wovh, out, nullptr, n, d, d);
}

// Round 3
// 399.539 us; speedup vs baseline: 1.1034x; 1.1034x over previous
//
#include <hip/hip_runtime.h>
#include <hip/hip_bf16.h>
#include <stdint.h>
#include <stddef.h>
#include <math.h>

typedef _Float16 f16;
typedef __attribute__((ext_vector_type(8))) _Float16 f16x8;  // 4 VGPRs (MFMA A/B)
typedef __attribute__((ext_vector_type(4))) float    f32x4;  // MFMA C/D

constexpr int BM = 128, BN = 128, BK = 64;   // legacy o-GEMM / half-splitk tiles

// async global->LDS DMA, 16 B/lane; LDS dest = wave-uniform base + lane*16
#define GLOAD_LDS16(gp, lp)                                        \
    __builtin_amdgcn_global_load_lds(                              \
        (const __attribute__((address_space(1))) unsigned int*)(gp),\
        (__attribute__((address_space(3))) unsigned int*)(lp), 16, 0, 0)

// one phase's MFMA cluster: 16 x mfma_f32_16x16x32_f16 wrapped in setprio (T5)
#define MFMA_TILE(AV, BV)                                                     \
    do {                                                                      \
        __builtin_amdgcn_s_setprio(1);                                        \
        _Pragma("unroll")                                                     \
        for (int mi_ = 0; mi_ < 4; ++mi_)                                     \
            _Pragma("unroll")                                                 \
            for (int ni_ = 0; ni_ < 4; ++ni_)                                 \
                acc[mi_][ni_] = __builtin_amdgcn_mfma_f32_16x16x32_f16(       \
                    (AV)[mi_], (BV)[ni_], acc[mi_][ni_], 0, 0, 0);            \
        __builtin_amdgcn_s_setprio(0);                                        \
    } while (0)

// ===========================================================================
// Pipelined 2-term GEMM (dense q product): C = (Ah+Al) @ B^T.
// BM=128, BN=256, BK=64, 512 threads = 8 waves (2M x 4N), 64x64 out/wave.
// LDS 128 KiB double-buffered: per buffer [Ah 16K][Al 16K][B 32K] bytes.
// 4 phases/K-tile, 16 MFMA each, counted vmcnt (ledger in round-1 notes),
// setprio around MFMA, XOR-swizzled LDS via pre-swizzled global source.
template <int EPI>
__global__ __launch_bounds__(512, 2) void gemm8_a2(
    const f16* __restrict__ Ah, const f16* __restrict__ Al,
    const f16* __restrict__ B,
    float* __restrict__ Cf, f16* __restrict__ Co, f16* __restrict__ Clo,
    int M, int N, int K)
{
    const int bx = blockIdx.x;
    const int by = blockIdx.y;

    const int tid   = threadIdx.x;
    const int lane  = tid & 63;
    const int wave  = tid >> 6;   // 0..7
    const int wm    = wave >> 2;  // 0..1  (M)
    const int wn    = wave & 3;   // 0..3  (N)
    const int lrow  = lane & 15;
    const int lquad = lane >> 4;

    __shared__ f16 lds[2][32768];   // 128 KiB total

    const int row0 = by * 128;
    const int col0 = bx * 256;

    const int srow = tid >> 3;                       // 0..63 (row within unit)
    const int scol = ((tid & 7) ^ (srow & 7)) * 8;   // pre-swizzled source col
    const int loff = wave * 512;                     // wave slice inside a unit

    const int g0 = ((lquad)     ^ (lrow & 7)) * 8;   // swizzled group, kk=0
    const int g1 = ((4 + lquad) ^ (lrow & 7)) * 8;   // swizzled group, kk=1

    const int arow = (wm * 64 + lrow) * 64;           // A frag base (elems)
    const int brow = (wn * 64 + lrow) * 64 + 16384;   // B frag base (elems)

    const f16* gAh = Ah + (size_t)(row0 + srow) * K + scol;
    const f16* gAl = Al + (size_t)(row0 + srow) * K + scol;
    const f16* gB  = B  + (size_t)(col0 + srow) * K + scol;
    const size_t r64 = (size_t)64 * K;

    f32x4 acc[4][4];
    const f32x4 fz = {0.f, 0.f, 0.f, 0.f};
    #pragma unroll
    for (int i = 0; i < 4; ++i)
        #pragma unroll
        for (int j = 0; j < 4; ++j) acc[i][j] = fz;

    const int nt = K / 64;

    // prologue: stage tile 0 into buffer 0
    #pragma unroll
    for (int u = 0; u < 4; ++u)
        GLOAD_LDS16(gB + u * r64, &lds[0][16384 + u * 4096 + loff]);
    #pragma unroll
    for (int u = 0; u < 2; ++u)
        GLOAD_LDS16(gAh + u * r64, &lds[0][u * 4096 + loff]);
    #pragma unroll
    for (int u = 0; u < 2; ++u)
        GLOAD_LDS16(gAl + u * r64, &lds[0][8192 + u * 4096 + loff]);
    asm volatile("s_waitcnt vmcnt(2)");   // B+Ah landed; Al(0) may fly
    __builtin_amdgcn_s_barrier();

    auto tile_body = [&](int t, bool stage) {
        const int cur = t & 1;
        const size_t kn = (size_t)(t + 1) * 64;
        const f16* bufc = &lds[cur][0];
        f16* bufn = &lds[cur ^ 1][0];

        f16x8 av[4], bv0[4], bv1[4];

        // ---------- phase A: Ah x kk0
        #pragma unroll
        for (int mi = 0; mi < 4; ++mi)
            av[mi] = *(const f16x8*)&bufc[arow + mi * 1024 + g0];
        #pragma unroll
        for (int ni = 0; ni < 4; ++ni)
            bv0[ni] = *(const f16x8*)&bufc[brow + ni * 1024 + g0];
        if (stage) {
            GLOAD_LDS16(gB + kn,       &bufn[16384 + loff]);
            GLOAD_LDS16(gB + r64 + kn, &bufn[16384 + 4096 + loff]);
        }
        __builtin_amdgcn_s_barrier();
        asm volatile("s_waitcnt lgkmcnt(0)");
        MFMA_TILE(av, bv0);
        __builtin_amdgcn_s_barrier();

        // ---------- phase B: Ah x kk1
        #pragma unroll
        for (int mi = 0; mi < 4; ++mi)
            av[mi] = *(const f16x8*)&bufc[arow + mi * 1024 + g1];
        #pragma unroll
        for (int ni = 0; ni < 4; ++ni)
            bv1[ni] = *(const f16x8*)&bufc[brow + ni * 1024 + g1];
        if (stage) {
            GLOAD_LDS16(gB + 2 * r64 + kn, &bufn[16384 +  8192 + loff]);
            GLOAD_LDS16(gB + 3 * r64 + kn, &bufn[16384 + 12288 + loff]);
            asm volatile("s_waitcnt vmcnt(4)");   // drain Al(t)
        } else {
            asm volatile("s_waitcnt vmcnt(0)");   // last tile: drain Al(t)
        }
        __builtin_amdgcn_s_barrier();
        asm volatile("s_waitcnt lgkmcnt(0)");
        MFMA_TILE(av, bv1);
        __builtin_amdgcn_s_barrier();

        // ---------- phase C: Al x kk0
        #pragma unroll
        for (int mi = 0; mi < 4; ++mi)
            av[mi] = *(const f16x8*)&bufc[8192 + arow + mi * 1024 + g0];
        if (stage) {
            GLOAD_LDS16(gAh + kn,       &bufn[loff]);
            GLOAD_LDS16(gAh + r64 + kn, &bufn[4096 + loff]);
        }
        __builtin_amdgcn_s_barrier();
        asm volatile("s_waitcnt lgkmcnt(0)");
        MFMA_TILE(av, bv0);
        __builtin_amdgcn_s_barrier();

        // ---------- phase D: Al x kk1
        #pragma unroll
        for (int mi = 0; mi < 4; ++mi)
            av[mi] = *(const f16x8*)&bufc[8192 + arow + mi * 1024 + g1];
        if (stage) {
            GLOAD_LDS16(gAl + kn,       &bufn[ 8192 + loff]);
            GLOAD_LDS16(gAl + r64 + kn, &bufn[12288 + loff]);
        }
        asm volatile("s_waitcnt vmcnt(2)");   // drain B(t+1)+Ah(t+1)
        __builtin_amdgcn_s_barrier();
        asm volatile("s_waitcnt lgkmcnt(0)");
        MFMA_TILE(av, bv1);
        __builtin_amdgcn_s_barrier();
    };

    for (int t = 0; t < nt - 1; ++t) tile_body(t, true);
    tile_body(nt - 1, false);

    // epilogue: D element (row = lquad*4 + r, col = lrow) within 16x16 tiles
    #pragma unroll
    for (int mi = 0; mi < 4; ++mi) {
        #pragma unroll
        for (int ni = 0; ni < 4; ++ni) {
            #pragma unroll
            for (int r = 0; r < 4; ++r) {
                const int row = row0 + wm * 64 + mi * 16 + lquad * 4 + r;
                const int col = col0 + wn * 64 + ni * 16 + lrow;
                const size_t idx = (size_t)row * N + col;
                const float v = acc[mi][ni][r];
                if (EPI == 0) {
                    Cf[idx] = v;
                } else {
                    const f16 h = (f16)v;
                    Co[idx]  = h;
                    Clo[idx] = (f16)(v - (float)h);
                }
            }
        }
    }
}

// ===========================================================================
// S-GEMM main dispatch: the 256 FULLY-LIVE causal jobs, one block each,
// perfectly balanced 1 block/CU (no grid quantization). Same inner pipeline
// as gemm8_a2. Job map: full jobs of row-pair r are (by=2r, bx=0..r-1) and
// (by=2r+1, bx=0..r): 2r+1 jobs, prefix sum r^2 -> r = floor(sqrt(j)).
// The 16 half-dead diagonal jobs (by=2r, bx=r) go to gemm_half_splitk.
// XCD remap: block b -> j = (b&7)*32 + (b>>3), so each XCD gets a contiguous
// j-range (neighboring jobs share A-panels -> L2 locality). Bijective: 256=8*32.
__global__ __launch_bounds__(512, 2) void gemm8_s_jobs(
    const f16* __restrict__ Ah, const f16* __restrict__ Al,
    const f16* __restrict__ B,
    float* __restrict__ Cf, int N, int K)
{
    const int b = blockIdx.x;
    const int j = (b & 7) * 32 + (b >> 3);
    int r = (int)sqrtf((float)j);
    while (r * r > j) --r;
    while ((r + 1) * (r + 1) <= j) ++r;
    const int u = j - r * r;
    const int by = (u < r) ? 2 * r : 2 * r + 1;
    const int bx = (u < r) ? u : u - r;

    const int tid   = threadIdx.x;
    const int lane  = tid & 63;
    const int wave  = tid >> 6;
    const int wm    = wave >> 2;
    const int wn    = wave & 3;
    const int lrow  = lane & 15;
    const int lquad = lane >> 4;

    __shared__ f16 lds[2][32768];   // 128 KiB

    const int row0 = by * 128;
    const int col0 = bx * 256;

    const int srow = tid >> 3;
    const int scol = ((tid & 7) ^ (srow & 7)) * 8;
    const int loff = wave * 512;

    const int g0 = ((lquad)     ^ (lrow & 7)) * 8;
    const int g1 = ((4 + lquad) ^ (lrow & 7)) * 8;

    const int arow = (wm * 64 + lrow) * 64;
    const int brow = (wn * 64 + lrow) * 64 + 16384;

    const f16* gAh = Ah + (size_t)(row0 + srow) * K + scol;
    const f16* gAl = Al + (size_t)(row0 + srow) * K + scol;
    const f16* gB  = B  + (size_t)(col0 + srow) * K + scol;
    const size_t r64 = (size_t)64 * K;

    f32x4 acc[4][4];
    const f32x4 fz = {0.f, 0.f, 0.f, 0.f};
    #pragma unroll
    for (int i = 0; i < 4; ++i)
        #pragma unroll
        for (int jj = 0; jj < 4; ++jj) acc[i][jj] = fz;

    const int nt = K / 64;

    #pragma unroll
    for (int u2 = 0; u2 < 4; ++u2)
        GLOAD_LDS16(gB + u2 * r64, &lds[0][16384 + u2 * 4096 + loff]);
    #pragma unroll
    for (int u2 = 0; u2 < 2; ++u2)
        GLOAD_LDS16(gAh + u2 * r64, &lds[0][u2 * 4096 + loff]);
    #pragma unroll
    for (int u2 = 0; u2 < 2; ++u2)
        GLOAD_LDS16(gAl + u2 * r64, &lds[0][8192 + u2 * 4096 + loff]);
    asm volatile("s_waitcnt vmcnt(2)");
    __builtin_amdgcn_s_barrier();

    auto tile_body = [&](int t, bool stage) {
        const int cur = t & 1;
        const size_t kn = (size_t)(t + 1) * 64;
        const f16* bufc = &lds[cur][0];
        f16* bufn = &lds[cur ^ 1][0];

        f16x8 av[4], bv0[4], bv1[4];

        // phase A
        #pragma unroll
        for (int mi = 0; mi < 4; ++mi)
            av[mi] = *(const f16x8*)&bufc[arow + mi * 1024 + g0];
        #pragma unroll
        for (int ni = 0; ni < 4; ++ni)
            bv0[ni] = *(const f16x8*)&bufc[brow + ni * 1024 + g0];
        if (stage) {
            GLOAD_LDS16(gB + kn,       &bufn[16384 + loff]);
            GLOAD_LDS16(gB + r64 + kn, &bufn[16384 + 4096 + loff]);
        }
        __builtin_amdgcn_s_barrier();
        asm volatile("s_waitcnt lgkmcnt(0)");
        MFMA_TILE(av, bv0);
        __builtin_amdgcn_s_barrier();

        // phase B
        #pragma unroll
        for (int mi = 0; mi < 4; ++mi)
            av[mi] = *(const f16x8*)&bufc[arow + mi * 1024 + g1];
        #pragma unroll
        for (int ni = 0; ni < 4; ++ni)
            bv1[ni] = *(const f16x8*)&bufc[brow + ni * 1024 + g1];
        if (stage) {
            GLOAD_LDS16(gB + 2 * r64 + kn, &bufn[16384 +  8192 + loff]);
            GLOAD_LDS16(gB + 3 * r64 + kn, &bufn[16384 + 12288 + loff]);
            asm volatile("s_waitcnt vmcnt(4)");
        } else {
            asm volatile("s_waitcnt vmcnt(0)");
        }
        __builtin_amdgcn_s_barrier();
        asm volatile("s_waitcnt lgkmcnt(0)");
        MFMA_TILE(av, bv1);
        __builtin_amdgcn_s_barrier();

        // phase C
        #pragma unroll
        for (int mi = 0; mi < 4; ++mi)
            av[mi] = *(const f16x8*)&bufc[8192 + arow + mi * 1024 + g0];
        if (stage) {
            GLOAD_LDS16(gAh + kn,       &bufn[loff]);
            GLOAD_LDS16(gAh + r64 + kn, &bufn[4096 + loff]);
        }
        __builtin_amdgcn_s_barrier();
        asm volatile("s_waitcnt lgkmcnt(0)");
        MFMA_TILE(av, bv0);
        __builtin_amdgcn_s_barrier();

        // phase D
        #pragma unroll
        for (int mi = 0; mi < 4; ++mi)
            av[mi] = *(const f16x8*)&bufc[8192 + arow + mi * 1024 + g1];
        if (stage) {
            GLOAD_LDS16(gAl + kn,       &bufn[ 8192 + loff]);
            GLOAD_LDS16(gAl + r64 + kn, &bufn[12288 + loff]);
        }
        asm volatile("s_waitcnt vmcnt(2)");
        __builtin_amdgcn_s_barrier();
        asm volatile("s_waitcnt lgkmcnt(0)");
        MFMA_TILE(av, bv1);
        __builtin_amdgcn_s_barrier();
    };

    for (int t = 0; t < nt - 1; ++t) tile_body(t, true);
    tile_body(nt - 1, false);

    #pragma unroll
    for (int mi = 0; mi < 4; ++mi) {
        #pragma unroll
        for (int ni = 0; ni < 4; ++ni) {
            #pragma unroll
            for (int rr = 0; rr < 4; ++rr) {
                const int row = row0 + wm * 64 + mi * 16 + lquad * 4 + rr;
                const int col = col0 + wn * 64 + ni * 16 + lrow;
                Cf[(size_t)row * N + col] = acc[mi][ni][rr];
            }
        }
    }
}

// ===========================================================================
// Split-K pass for the 16 half-dead diagonal jobs (by=2h, bx=h): live region
// is the 128x128 square at (row0=256h, col0=256h). grid = (8 kchunks, 16 jobs);
// each block computes a 128x128 x 256-K 2-term partial into its own slice of
// Spart (no atomics, no zero-init). 256 thr, 4 waves (2x2), BK=64, 48 KiB LDS.
__global__ __launch_bounds__(256) void gemm_half_splitk(
    const f16* __restrict__ Ah, const f16* __restrict__ Al,
    const f16* __restrict__ B, float* __restrict__ Spart, int Kg)
{
    const int kc = blockIdx.x;       // 0..7
    const int h  = blockIdx.y;       // 0..15
    const int row0 = h * 256;        // == col0
    const int kbeg = kc * 256;

    const int tid   = threadIdx.x;
    const int lane  = tid & 63;
    const int wave  = tid >> 6;
    const int wm    = wave >> 1;
    const int wn    = wave & 1;
    const int lrow  = lane & 15;
    const int lquad = lane >> 4;

    __shared__ f16 sAh[BM * BK];
    __shared__ f16 sAl[BM * BK];
    __shared__ f16 sB [BM * BK];

    const int srow = tid >> 3;
    const int scol = (((tid & 7) ^ ((tid >> 3) & 7))) * 8;
    const int lbase = wave * 512;

    f32x4 acc[4][4];
    const f32x4 fz = {0.f, 0.f, 0.f, 0.f};
    #pragma unroll
    for (int i = 0; i < 4; ++i)
        #pragma unroll
        for (int jj = 0; jj < 4; ++jj) acc[i][jj] = fz;

    for (int k0 = kbeg; k0 < kbeg + 256; k0 += BK) {
        __syncthreads();
        #pragma unroll
        for (int r = 0; r < 4; ++r) {
            const int trow = srow + 32 * r;
            const size_t ga = (size_t)(row0 + trow) * Kg + k0 + scol;
            const int ldst = lbase + r * 2048;
            GLOAD_LDS16(&Ah[ga], &sAh[ldst]);
            GLOAD_LDS16(&Al[ga], &sAl[ldst]);
            GLOAD_LDS16(&B [ga], &sB [ldst]);   // B rows == A rows (diag)
        }
        __syncthreads();

        #pragma unroll
        for (int kk = 0; kk < 2; ++kk) {
            const int grpA = ((kk * 4 + lquad) ^ (lrow & 7)) * 8;
            f16x8 ah[4], al[4], bv[4];
            #pragma unroll
            for (int mi = 0; mi < 4; ++mi) {
                const int off = (wm * 64 + mi * 16 + lrow) * BK + grpA;
                ah[mi] = *reinterpret_cast<const f16x8*>(&sAh[off]);
                al[mi] = *reinterpret_cast<const f16x8*>(&sAl[off]);
            }
            #pragma unroll
            for (int ni = 0; ni < 4; ++ni)
                bv[ni] = *reinterpret_cast<const f16x8*>(
                    &sB[(wn * 64 + ni * 16 + lrow) * BK + grpA]);

            #pragma unroll
            for (int mi = 0; mi < 4; ++mi)
                #pragma unroll
                for (int ni = 0; ni < 4; ++ni) {
                    acc[mi][ni] = __builtin_amdgcn_mfma_f32_16x16x32_f16(
                        ah[mi], bv[ni], acc[mi][ni], 0, 0, 0);
                    acc[mi][ni] = __builtin_amdgcn_mfma_f32_16x16x32_f16(
                        al[mi], bv[ni], acc[mi][ni], 0, 0, 0);
                }
        }
    }

    float* out = Spart + ((size_t)(kc * 16 + h)) * (128 * 128);
    #pragma unroll
    for (int mi = 0; mi < 4; ++mi) {
        #pragma unroll
        for (int ni = 0; ni < 4; ++ni) {
            #pragma unroll
            for (int r = 0; r < 4; ++r) {
                const int row = wm * 64 + mi * 16 + lquad * 4 + r;
                const int col = wn * 64 + ni * 16 + lrow;
                out[row * 128 + col] = acc[mi][ni][r];
            }
        }
    }
}

// sum the 8 K-chunk partials of each half job into S. grid = (16, 16 jobs).
__global__ __launch_bounds__(256) void combine_halves(
    const float* __restrict__ Spart, float* __restrict__ S, int n)
{
    const int h = blockIdx.y;
    const int e = (blockIdx.x * 256 + threadIdx.x) * 4;   // 0..16383
    float4 a = *reinterpret_cast<const float4*>(
        &Spart[(size_t)h * (128 * 128) + e]);
    #pragma unroll
    for (int kc = 1; kc < 8; ++kc) {
        const float4 b = *reinterpret_cast<const float4*>(
            &Spart[(size_t)(kc * 16 + h) * (128 * 128) + e]);
        a.x += b.x; a.y += b.y; a.z += b.z; a.w += b.w;
    }
    const int i = e >> 7, jj = e & 127;
    *reinterpret_cast<float4*>(&S[(size_t)(h * 256 + i) * n + h * 256 + jj]) = a;
}

// ===========================================================================
// Pipelined single-term GEMM: C = A @ B^T, TRIPLE-buffered LDS (144 KiB).
// 2 phases/K-tile, 16 MFMA each; staging 2 tiles ahead; vmcnt(6) steady.
template <int EPI>
__global__ __launch_bounds__(512, 2) void gemm8_1t(
    const f16* __restrict__ A, const f16* __restrict__ B,
    float* __restrict__ Cf, f16* __restrict__ Co,
    int M, int N, int K)
{
    const int bx = blockIdx.x;
    const int by = blockIdx.y;

    const int tid   = threadIdx.x;
    const int lane  = tid & 63;
    const int wave  = tid >> 6;
    const int wm    = wave >> 2;
    const int wn    = wave & 3;
    const int lrow  = lane & 15;
    const int lquad = lane >> 4;

    __shared__ f16 lds[3][24576];   // 144 KiB total

    const int row0 = by * 128;
    const int col0 = bx * 256;

    const int srow = tid >> 3;
    const int scol = ((tid & 7) ^ (srow & 7)) * 8;
    const int loff = wave * 512;
    const int g0 = ((lquad)     ^ (lrow & 7)) * 8;
    const int g1 = ((4 + lquad) ^ (lrow & 7)) * 8;
    const int arow = (wm * 64 + lrow) * 64;
    const int brow = (wn * 64 + lrow) * 64 + 8192;

    const f16* gA = A + (size_t)(row0 + srow) * K + scol;
    const f16* gB = B + (size_t)(col0 + srow) * K + scol;
    const size_t r64 = (size_t)64 * K;

    f32x4 acc[4][4];
    const f32x4 fz = {0.f, 0.f, 0.f, 0.f};
    #pragma unroll
    for (int i = 0; i < 4; ++i)
        #pragma unroll
        for (int j = 0; j < 4; ++j) acc[i][j] = fz;

    const int nt = K / 64;

    // prologue: stage tiles 0 and 1 (order per tile: B0 B1 B2 B3 A0 A1)
    #pragma unroll
    for (int tt = 0; tt < 2; ++tt) {
        const size_t kk = (size_t)tt * 64;
        #pragma unroll
        for (int u = 0; u < 4; ++u)
            GLOAD_LDS16(gB + u * r64 + kk, &lds[tt][8192 + u * 4096 + loff]);
        #pragma unroll
        for (int u = 0; u < 2; ++u)
            GLOAD_LDS16(gA + u * r64 + kk, &lds[tt][u * 4096 + loff]);
    }
    asm volatile("s_waitcnt vmcnt(6)");   // tile 0 landed; tile 1 may fly
    __builtin_amdgcn_s_barrier();

    int cur = 0;
    for (int t = 0; t < nt; ++t) {
        const int nb = (cur >= 1) ? (cur - 1) : (cur + 2);  // (t+2) % 3
        const bool stage2 = (t + 2 < nt);
        const size_t kn = (size_t)(t + 2) * 64;
        const f16* bufc = &lds[cur][0];
        f16* bufn = &lds[nb][0];

        f16x8 av[4], bv[4];

        // ---------- phase A: kk0
        #pragma unroll
        for (int mi = 0; mi < 4; ++mi)
            av[mi] = *(const f16x8*)&bufc[arow + mi * 1024 + g0];
        #pragma unroll
        for (int ni = 0; ni < 4; ++ni)
            bv[ni] = *(const f16x8*)&bufc[brow + ni * 1024 + g0];
        if (stage2) {
            GLOAD_LDS16(gB + kn,           &bufn[8192 + loff]);
            GLOAD_LDS16(gB + r64 + kn,     &bufn[8192 + 4096 + loff]);
            GLOAD_LDS16(gB + 2 * r64 + kn, &bufn[8192 + 8192 + loff]);
        }
        __builtin_amdgcn_s_barrier();
        asm volatile("s_waitcnt lgkmcnt(0)");
        MFMA_TILE(av, bv);
        __builtin_amdgcn_s_barrier();

        // ---------- phase B: kk1
        #pragma unroll
        for (int mi = 0; mi < 4; ++mi)
            av[mi] = *(const f16x8*)&bufc[arow + mi * 1024 + g1];
        #pragma unroll
        for (int ni = 0; ni < 4; ++ni)
            bv[ni] = *(const f16x8*)&bufc[brow + ni * 1024 + g1];
        if (stage2) {
            GLOAD_LDS16(gB + 3 * r64 + kn, &bufn[8192 + 12288 + loff]);
            GLOAD_LDS16(gA + kn,           &bufn[loff]);
            GLOAD_LDS16(gA + r64 + kn,     &bufn[4096 + loff]);
            asm volatile("s_waitcnt vmcnt(6)");   // drain tile t+1
        } else {
            asm volatile("s_waitcnt vmcnt(0)");   // pipeline tail drain
        }
        __builtin_amdgcn_s_barrier();
        asm volatile("s_waitcnt lgkmcnt(0)");
        MFMA_TILE(av, bv);
        __builtin_amdgcn_s_barrier();

        cur = (cur == 2) ? 0 : cur + 1;
    }

    #pragma unroll
    for (int mi = 0; mi < 4; ++mi) {
        #pragma unroll
        for (int ni = 0; ni < 4; ++ni) {
            #pragma unroll
            for (int r = 0; r < 4; ++r) {
                const int row = row0 + wm * 64 + mi * 16 + lquad * 4 + r;
                const int col = col0 + wn * 64 + ni * 16 + lrow;
                const size_t idx = (size_t)row * N + col;
                const float v = acc[mi][ni][r];
                if (EPI == 0) Cf[idx] = v;
                else          Co[idx] = (f16)v;
            }
        }
    }
}

// ===========================================================================
// Legacy 128x128 GEMM kept for the K-causal o = P @ xT^T product (triangular
// K; 4-5 blocks/CU + heavy-first order balance it naturally).
template <int EPI, bool KCAUSAL>
__global__ __launch_bounds__(256) void gemm_plain(
    const f16* __restrict__ A, const f16* __restrict__ B,
    float* __restrict__ Cf, f16* __restrict__ Co,
    int M, int N, int K)
{
    const int bx = blockIdx.x;
    const int by = KCAUSAL ? (gridDim.y - 1 - blockIdx.y) : blockIdx.y;

    const int tid   = threadIdx.x;
    const int lane  = tid & 63;
    const int wave  = tid >> 6;
    const int wm    = wave >> 1;
    const int wn    = wave & 1;
    const int lrow  = lane & 15;
    const int lquad = lane >> 4;

    __shared__ f16 sA[BM * BK];   // 16 KB each, 32 KB total
    __shared__ f16 sB[BN * BK];

    const int row0 = by * BM;
    const int col0 = bx * BN;

    const int srow = tid >> 3;
    const int scol = (((tid & 7) ^ ((tid >> 3) & 7))) * 8;
    const int lbase = wave * 512;

    f32x4 acc[4][4];
    const f32x4 fzero = {0.f, 0.f, 0.f, 0.f};
    #pragma unroll
    for (int i = 0; i < 4; ++i)
        #pragma unroll
        for (int j = 0; j < 4; ++j) acc[i][j] = fzero;

    const int Keff = KCAUSAL ? (by + 1) * BM : K;

    for (int k0 = 0; k0 < Keff; k0 += BK) {
        __syncthreads();
        #pragma unroll
        for (int r = 0; r < 4; ++r) {
            const int trow = srow + 32 * r;
            GLOAD_LDS16(&A[(size_t)(row0 + trow) * K + k0 + scol], &sA[lbase + r * 2048]);
            GLOAD_LDS16(&B[(size_t)(col0 + trow) * K + k0 + scol], &sB[lbase + r * 2048]);
        }
        __syncthreads();

        #pragma unroll
        for (int kk = 0; kk < 2; ++kk) {
            const int grpA = ((kk * 4 + lquad) ^ (lrow & 7)) * 8;
            f16x8 av[4], bv[4];
            #pragma unroll
            for (int mi = 0; mi < 4; ++mi)
                av[mi] = *reinterpret_cast<const f16x8*>(
                    &sA[(wm * 64 + mi * 16 + lrow) * BK + grpA]);
            #pragma unroll
            for (int ni = 0; ni < 4; ++ni)
                bv[ni] = *reinterpret_cast<const f16x8*>(
                    &sB[(wn * 64 + ni * 16 + lrow) * BK + grpA]);

            #pragma unroll
            for (int mi = 0; mi < 4; ++mi)
                #pragma unroll
                for (int ni = 0; ni < 4; ++ni)
                    acc[mi][ni] = __builtin_amdgcn_mfma_f32_16x16x32_f16(
                        av[mi], bv[ni], acc[mi][ni], 0, 0, 0);
        }
    }

    #pragma unroll
    for (int mi = 0; mi < 4; ++mi) {
        #pragma unroll
        for (int ni = 0; ni < 4; ++ni) {
            #pragma unroll
            for (int r = 0; r < 4; ++r) {
                const int row = row0 + wm * 64 + mi * 16 + lquad * 4 + r;
                const int col = col0 + wn * 64 + ni * 16 + lrow;
                const size_t idx = (size_t)row * N + col;
                const float v = acc[mi][ni][r];
                if (EPI == 0) Cf[idx] = v;
                else          Co[idx] = (f16)v;
            }
        }
    }
}

// fp32 -> f16 hi (+ optional lo residual), 4 elems/thread
__global__ __launch_bounds__(256) void split_f32_f16(
    const float* __restrict__ in, f16* __restrict__ hi, f16* __restrict__ lo,
    size_t nelem)
{
    const size_t i = ((size_t)blockIdx.x * 256 + threadIdx.x) * 4;
    if (i >= nelem) return;
    const float4 v = *reinterpret_cast<const float4*>(in + i);
    union { f16 h[4]; ushort4 u; } H, L;
    H.h[0] = (f16)v.x; H.h[1] = (f16)v.y; H.h[2] = (f16)v.z; H.h[3] = (f16)v.w;
    *reinterpret_cast<ushort4*>(hi + i) = H.u;
    if (lo) {
        L.h[0] = (f16)(v.x - (float)H.h[0]);
        L.h[1] = (f16)(v.y - (float)H.h[1]);
        L.h[2] = (f16)(v.z - (float)H.h[2]);
        L.h[3] = (f16)(v.w - (float)H.h[3]);
        *reinterpret_cast<ushort4*>(lo + i) = L.u;
    }
}

// row-wise causal softmax, single global pass (row cached in LDS),
// online max+sum; zero-pads P to the 128 boundary.
__global__ __launch_bounds__(256) void softmax_rows(
    const float* __restrict__ S, f16* __restrict__ P, int n)
{
    const int row = blockIdx.x;
    const int len = row + 1;
    const int padlen = ((row >> 7) + 1) << 7;
    const float* srow = S + (size_t)row * n;
    f16* prow = P + (size_t)row * n;
    const int tid = threadIdx.x;
    const int lane = tid & 63, wave = tid >> 6;
    __shared__ float rowbuf[4096];   // 16 KB row cache (n <= 4096)
    __shared__ float redm[4], reds[4];

    float m = -3.0e38f, s = 0.f;
    for (int j = tid; j < len; j += 256) {
        const float v = srow[j];
        rowbuf[j] = v;
        const float mn = fmaxf(m, v);
        s = s * __expf(m - mn) + __expf(v - mn);
        m = mn;
    }
    #pragma unroll
    for (int off = 32; off; off >>= 1) {
        const float mo = __shfl_xor(m, off, 64);
        const float so = __shfl_xor(s, off, 64);
        const float mn = fmaxf(m, mo);
        s = s * __expf(m - mn) + so * __expf(mo - mn);
        m = mn;
    }
    if (lane == 0) { redm[wave] = m; reds[wave] = s; }
    __syncthreads();
    float M = redm[0], Sm = reds[0];
    #pragma unroll
    for (int w = 1; w < 4; ++w) {
        const float mn = fmaxf(M, redm[w]);
        Sm = Sm * __expf(M - mn) + reds[w] * __expf(redm[w] - mn);
        M = mn;
    }
    const float inv = 1.0f / Sm;

    const f16 z = (f16)0.0f;
    for (int j = tid; j < padlen; j += 256)
        prow[j] = (j < len) ? (f16)(__expf(rowbuf[j] - M) * inv) : z;
}

// out[c*rows + r] = (f16)in[r*cols + c]   (fp32 in, f16 out)
__global__ __launch_bounds__(256) void transpose_f32_f16(
    const float* __restrict__ in, f16* __restrict__ out, int rows, int cols)
{
    __shared__ float tile[32][33];
    const int bx = blockIdx.x;
    const int by = blockIdx.y;
    const int tx = threadIdx.x & 31;
    const int ty = threadIdx.x >> 5;
    #pragma unroll
    for (int r = 0; r < 4; ++r)
        tile[ty + 8 * r][tx] = in[(size_t)(by * 32 + ty + 8 * r) * cols + bx * 32 + tx];
    __syncthreads();
    #pragma unroll
    for (int r = 0; r < 4; ++r)
        out[(size_t)(bx * 32 + ty + 8 * r) * rows + by * 32 + tx] =
            (f16)tile[tx][ty + 8 * r];
}

extern "C" void kernel_launch(void* const* d_in, const int* in_sizes, int n_in,
                              void* d_out, int out_size, void* d_ws, size_t ws_size,
                              hipStream_t stream)
{
    const int n = 4096, d = 2048;
    const float* x   = (const float*)d_in[0];
    const float* Wqk = (const float*)d_in[1];
    const float* Wov = (const float*)d_in[2];
    float* out = (float*)d_out;

    char* ws = (char*)d_ws;
    const size_t MB = 1 << 20;
    f16*   xh   = (f16*)  (ws);             // 16 MB  (n x d)
    f16*   xl   = (f16*)  (ws + 16 * MB);   // 16 MB  (dead after q GEMM)
    f16*   Wh   = (f16*)  (ws + 32 * MB);   //  8 MB  (d x d, dead after q GEMM)
    f16*   Wovh = (f16*)  (ws + 40 * MB);   //  8 MB  (live to end)
    f16*   xTh  = (f16*)  (ws + 48 * MB);   // 16 MB  (d x n, live to o GEMM)
    f16*   qh   = (f16*)  (ws + 64 * MB);   // 16 MB  (dead after S GEMM)
    f16*   ql   = (f16*)  (ws + 80 * MB);   // 16 MB  (dead after S GEMM)
    float* S    = (float*)(ws + 96 * MB);   // 64 MB  (n x n)  -> peak 160 MB
    float* Sp   = (float*)(ws + 16 * MB);   //  8 MB  split-K partials (over xl,
                                            //        dead; freed before P)
    f16*   P    = (f16*)  (ws);             // 32 MB  (n x n), over xh+xl (dead)
    f16*   o    = (f16*)  (ws + 64 * MB);   // 16 MB  (n x d), over qh (dead)

    const dim3 blk(256);
    const dim3 blk8(512);

    // fp32 -> f16 conversions
    split_f32_f16<<<dim3((n * d) / (256 * 4)), blk, 0, stream>>>(x,   xh, xl, (size_t)n * d);
    split_f32_f16<<<dim3((d * d) / (256 * 4)), blk, 0, stream>>>(Wqk, Wh, nullptr, (size_t)d * d);
    split_f32_f16<<<dim3((d * d) / (256 * 4)), blk, 0, stream>>>(Wov, Wovh, nullptr, (size_t)d * d);
    transpose_f32_f16<<<dim3(d / 32, n / 32), blk, 0, stream>>>(x, xTh, n, d);

    // q = (xh+xl) @ Wh^T, pipelined 2-term, output split f16 hi/lo
    gemm8_a2<1><<<dim3(d / 256, n / 128), blk8, 0, stream>>>(
        xh, xl, Wh, nullptr, qh, ql, n, d, d);

    // S: 256 fully-live causal jobs, 1 block/CU, perfectly balanced
    gemm8_s_jobs<<<dim3(256), blk8, 0, stream>>>(qh, ql, xh, S, n, d);
    // 16 half-dead diagonal jobs, split-K 8-way, then combine into S
    gemm_half_splitk<<<dim3(8, 16), blk, 0, stream>>>(qh, ql, xh, Sp, d);
    combine_halves<<<dim3(16, 16), blk, 0, stream>>>(Sp, S, n);

    // P = causal row softmax(S), f16, zero-padded to 128 boundary
    softmax_rows<<<dim3(n), blk, 0, stream>>>(S, P, n);

    // o = P @ xTh^T  (K limited causally per row-block), f16
    gemm_plain<2, true><<<dim3(d / BN, n / BM), blk, 0, stream>>>(
        P, xTh, nullptr, o, n, d, n);

    // out = o @ Wovh^T, pipelined single-term, fp32 store to d_out
    gemm8_1t<0><<<dim3(d / 256, n / 128), blk8, 0, stream>>>(
        o, Wovh, out, nullptr, n, d, d);
}

// Round 4
// 380.415 us; speedup vs baseline: 1.1589x; 1.0503x over previous
//
#include <hip/hip_runtime.h>
#include <hip/hip_bf16.h>
#include <stdint.h>
#include <stddef.h>
#include <math.h>

typedef _Float16 f16;
typedef __attribute__((ext_vector_type(8))) _Float16 f16x8;  // 4 VGPRs (MFMA A/B)
typedef __attribute__((ext_vector_type(4))) float    f32x4;  // MFMA C/D

constexpr int BM = 128, BN = 128, BK = 64;   // half-splitk tiles

// async global->LDS DMA, 16 B/lane; LDS dest = wave-uniform base + lane*16
#define GLOAD_LDS16(gp, lp)                                        \
    __builtin_amdgcn_global_load_lds(                              \
        (const __attribute__((address_space(1))) unsigned int*)(gp),\
        (__attribute__((address_space(3))) unsigned int*)(lp), 16, 0, 0)

// one phase's MFMA cluster: 16 x mfma_f32_16x16x32_f16 wrapped in setprio (T5)
#define MFMA_TILE(AV, BV)                                                     \
    do {                                                                      \
        __builtin_amdgcn_s_setprio(1);                                        \
        _Pragma("unroll")                                                     \
        for (int mi_ = 0; mi_ < 4; ++mi_)                                     \
            _Pragma("unroll")                                                 \
            for (int ni_ = 0; ni_ < 4; ++ni_)                                 \
                acc[mi_][ni_] = __builtin_amdgcn_mfma_f32_16x16x32_f16(       \
                    (AV)[mi_], (BV)[ni_], acc[mi_][ni_], 0, 0, 0);            \
        __builtin_amdgcn_s_setprio(0);                                        \
    } while (0)

// ===========================================================================
// Pipelined 2-term GEMM (dense q product): C = (Ah+Al) @ B^T.
// BM=128, BN=256, BK=64, 512 threads = 8 waves (2M x 4N), 64x64 out/wave.
// LDS 128 KiB double-buffered: per buffer [Ah 16K][Al 16K][B 32K] bytes.
// 4 phases/K-tile, 16 MFMA each, counted vmcnt, setprio around MFMA,
// XOR-swizzled LDS via pre-swizzled global source.
template <int EPI>
__global__ __launch_bounds__(512, 2) void gemm8_a2(
    const f16* __restrict__ Ah, const f16* __restrict__ Al,
    const f16* __restrict__ B,
    float* __restrict__ Cf, f16* __restrict__ Co, f16* __restrict__ Clo,
    int M, int N, int K)
{
    const int bx = blockIdx.x;
    const int by = blockIdx.y;

    const int tid   = threadIdx.x;
    const int lane  = tid & 63;
    const int wave  = tid >> 6;   // 0..7
    const int wm    = wave >> 2;  // 0..1  (M)
    const int wn    = wave & 3;   // 0..3  (N)
    const int lrow  = lane & 15;
    const int lquad = lane >> 4;

    __shared__ f16 lds[2][32768];   // 128 KiB total

    const int row0 = by * 128;
    const int col0 = bx * 256;

    const int srow = tid >> 3;                       // 0..63 (row within unit)
    const int scol = ((tid & 7) ^ (srow & 7)) * 8;   // pre-swizzled source col
    const int loff = wave * 512;                     // wave slice inside a unit

    const int g0 = ((lquad)     ^ (lrow & 7)) * 8;   // swizzled group, kk=0
    const int g1 = ((4 + lquad) ^ (lrow & 7)) * 8;   // swizzled group, kk=1

    const int arow = (wm * 64 + lrow) * 64;           // A frag base (elems)
    const int brow = (wn * 64 + lrow) * 64 + 16384;   // B frag base (elems)

    const f16* gAh = Ah + (size_t)(row0 + srow) * K + scol;
    const f16* gAl = Al + (size_t)(row0 + srow) * K + scol;
    const f16* gB  = B  + (size_t)(col0 + srow) * K + scol;
    const size_t r64 = (size_t)64 * K;

    f32x4 acc[4][4];
    const f32x4 fz = {0.f, 0.f, 0.f, 0.f};
    #pragma unroll
    for (int i = 0; i < 4; ++i)
        #pragma unroll
        for (int j = 0; j < 4; ++j) acc[i][j] = fz;

    const int nt = K / 64;

    // prologue: stage tile 0 into buffer 0
    #pragma unroll
    for (int u = 0; u < 4; ++u)
        GLOAD_LDS16(gB + u * r64, &lds[0][16384 + u * 4096 + loff]);
    #pragma unroll
    for (int u = 0; u < 2; ++u)
        GLOAD_LDS16(gAh + u * r64, &lds[0][u * 4096 + loff]);
    #pragma unroll
    for (int u = 0; u < 2; ++u)
        GLOAD_LDS16(gAl + u * r64, &lds[0][8192 + u * 4096 + loff]);
    asm volatile("s_waitcnt vmcnt(2)");   // B+Ah landed; Al(0) may fly
    __builtin_amdgcn_s_barrier();

    auto tile_body = [&](int t, bool stage) {
        const int cur = t & 1;
        const size_t kn = (size_t)(t + 1) * 64;
        const f16* bufc = &lds[cur][0];
        f16* bufn = &lds[cur ^ 1][0];

        f16x8 av[4], bv0[4], bv1[4];

        // ---------- phase A: Ah x kk0
        #pragma unroll
        for (int mi = 0; mi < 4; ++mi)
            av[mi] = *(const f16x8*)&bufc[arow + mi * 1024 + g0];
        #pragma unroll
        for (int ni = 0; ni < 4; ++ni)
            bv0[ni] = *(const f16x8*)&bufc[brow + ni * 1024 + g0];
        if (stage) {
            GLOAD_LDS16(gB + kn,       &bufn[16384 + loff]);
            GLOAD_LDS16(gB + r64 + kn, &bufn[16384 + 4096 + loff]);
        }
        __builtin_amdgcn_s_barrier();
        asm volatile("s_waitcnt lgkmcnt(0)");
        MFMA_TILE(av, bv0);
        __builtin_amdgcn_s_barrier();

        // ---------- phase B: Ah x kk1
        #pragma unroll
        for (int mi = 0; mi < 4; ++mi)
            av[mi] = *(const f16x8*)&bufc[arow + mi * 1024 + g1];
        #pragma unroll
        for (int ni = 0; ni < 4; ++ni)
            bv1[ni] = *(const f16x8*)&bufc[brow + ni * 1024 + g1];
        if (stage) {
            GLOAD_LDS16(gB + 2 * r64 + kn, &bufn[16384 +  8192 + loff]);
            GLOAD_LDS16(gB + 3 * r64 + kn, &bufn[16384 + 12288 + loff]);
            asm volatile("s_waitcnt vmcnt(4)");   // drain Al(t)
        } else {
            asm volatile("s_waitcnt vmcnt(0)");   // last tile: drain Al(t)
        }
        __builtin_amdgcn_s_barrier();
        asm volatile("s_waitcnt lgkmcnt(0)");
        MFMA_TILE(av, bv1);
        __builtin_amdgcn_s_barrier();

        // ---------- phase C: Al x kk0
        #pragma unroll
        for (int mi = 0; mi < 4; ++mi)
            av[mi] = *(const f16x8*)&bufc[8192 + arow + mi * 1024 + g0];
        if (stage) {
            GLOAD_LDS16(gAh + kn,       &bufn[loff]);
            GLOAD_LDS16(gAh + r64 + kn, &bufn[4096 + loff]);
        }
        __builtin_amdgcn_s_barrier();
        asm volatile("s_waitcnt lgkmcnt(0)");
        MFMA_TILE(av, bv0);
        __builtin_amdgcn_s_barrier();

        // ---------- phase D: Al x kk1
        #pragma unroll
        for (int mi = 0; mi < 4; ++mi)
            av[mi] = *(const f16x8*)&bufc[8192 + arow + mi * 1024 + g1];
        if (stage) {
            GLOAD_LDS16(gAl + kn,       &bufn[ 8192 + loff]);
            GLOAD_LDS16(gAl + r64 + kn, &bufn[12288 + loff]);
        }
        asm volatile("s_waitcnt vmcnt(2)");   // drain B(t+1)+Ah(t+1)
        __builtin_amdgcn_s_barrier();
        asm volatile("s_waitcnt lgkmcnt(0)");
        MFMA_TILE(av, bv1);
        __builtin_amdgcn_s_barrier();
    };

    for (int t = 0; t < nt - 1; ++t) tile_body(t, true);
    tile_body(nt - 1, false);

    // epilogue: D element (row = lquad*4 + r, col = lrow) within 16x16 tiles
    #pragma unroll
    for (int mi = 0; mi < 4; ++mi) {
        #pragma unroll
        for (int ni = 0; ni < 4; ++ni) {
            #pragma unroll
            for (int r = 0; r < 4; ++r) {
                const int row = row0 + wm * 64 + mi * 16 + lquad * 4 + r;
                const int col = col0 + wn * 64 + ni * 16 + lrow;
                const size_t idx = (size_t)row * N + col;
                const float v = acc[mi][ni][r];
                if (EPI == 0) {
                    Cf[idx] = v;
                } else {
                    const f16 h = (f16)v;
                    Co[idx]  = h;
                    Clo[idx] = (f16)(v - (float)h);
                }
            }
        }
    }
}

// ===========================================================================
// S-GEMM main dispatch: the 256 FULLY-LIVE causal jobs, one block each,
// perfectly balanced 1 block/CU. Job map: r = floor(sqrt(j)); u = j - r^2;
// (by,bx) = u<r ? (2r, u) : (2r+1, u-r). XCD remap b -> j = (b&7)*32 + (b>>3).
__global__ __launch_bounds__(512, 2) void gemm8_s_jobs(
    const f16* __restrict__ Ah, const f16* __restrict__ Al,
    const f16* __restrict__ B,
    float* __restrict__ Cf, int N, int K)
{
    const int b = blockIdx.x;
    const int j = (b & 7) * 32 + (b >> 3);
    int r = (int)sqrtf((float)j);
    while (r * r > j) --r;
    while ((r + 1) * (r + 1) <= j) ++r;
    const int u = j - r * r;
    const int by = (u < r) ? 2 * r : 2 * r + 1;
    const int bx = (u < r) ? u : u - r;

    const int tid   = threadIdx.x;
    const int lane  = tid & 63;
    const int wave  = tid >> 6;
    const int wm    = wave >> 2;
    const int wn    = wave & 3;
    const int lrow  = lane & 15;
    const int lquad = lane >> 4;

    __shared__ f16 lds[2][32768];   // 128 KiB

    const int row0 = by * 128;
    const int col0 = bx * 256;

    const int srow = tid >> 3;
    const int scol = ((tid & 7) ^ (srow & 7)) * 8;
    const int loff = wave * 512;

    const int g0 = ((lquad)     ^ (lrow & 7)) * 8;
    const int g1 = ((4 + lquad) ^ (lrow & 7)) * 8;

    const int arow = (wm * 64 + lrow) * 64;
    const int brow = (wn * 64 + lrow) * 64 + 16384;

    const f16* gAh = Ah + (size_t)(row0 + srow) * K + scol;
    const f16* gAl = Al + (size_t)(row0 + srow) * K + scol;
    const f16* gB  = B  + (size_t)(col0 + srow) * K + scol;
    const size_t r64 = (size_t)64 * K;

    f32x4 acc[4][4];
    const f32x4 fz = {0.f, 0.f, 0.f, 0.f};
    #pragma unroll
    for (int i = 0; i < 4; ++i)
        #pragma unroll
        for (int jj = 0; jj < 4; ++jj) acc[i][jj] = fz;

    const int nt = K / 64;

    #pragma unroll
    for (int u2 = 0; u2 < 4; ++u2)
        GLOAD_LDS16(gB + u2 * r64, &lds[0][16384 + u2 * 4096 + loff]);
    #pragma unroll
    for (int u2 = 0; u2 < 2; ++u2)
        GLOAD_LDS16(gAh + u2 * r64, &lds[0][u2 * 4096 + loff]);
    #pragma unroll
    for (int u2 = 0; u2 < 2; ++u2)
        GLOAD_LDS16(gAl + u2 * r64, &lds[0][8192 + u2 * 4096 + loff]);
    asm volatile("s_waitcnt vmcnt(2)");
    __builtin_amdgcn_s_barrier();

    auto tile_body = [&](int t, bool stage) {
        const int cur = t & 1;
        const size_t kn = (size_t)(t + 1) * 64;
        const f16* bufc = &lds[cur][0];
        f16* bufn = &lds[cur ^ 1][0];

        f16x8 av[4], bv0[4], bv1[4];

        // phase A
        #pragma unroll
        for (int mi = 0; mi < 4; ++mi)
            av[mi] = *(const f16x8*)&bufc[arow + mi * 1024 + g0];
        #pragma unroll
        for (int ni = 0; ni < 4; ++ni)
            bv0[ni] = *(const f16x8*)&bufc[brow + ni * 1024 + g0];
        if (stage) {
            GLOAD_LDS16(gB + kn,       &bufn[16384 + loff]);
            GLOAD_LDS16(gB + r64 + kn, &bufn[16384 + 4096 + loff]);
        }
        __builtin_amdgcn_s_barrier();
        asm volatile("s_waitcnt lgkmcnt(0)");
        MFMA_TILE(av, bv0);
        __builtin_amdgcn_s_barrier();

        // phase B
        #pragma unroll
        for (int mi = 0; mi < 4; ++mi)
            av[mi] = *(const f16x8*)&bufc[arow + mi * 1024 + g1];
        #pragma unroll
        for (int ni = 0; ni < 4; ++ni)
            bv1[ni] = *(const f16x8*)&bufc[brow + ni * 1024 + g1];
        if (stage) {
            GLOAD_LDS16(gB + 2 * r64 + kn, &bufn[16384 +  8192 + loff]);
            GLOAD_LDS16(gB + 3 * r64 + kn, &bufn[16384 + 12288 + loff]);
            asm volatile("s_waitcnt vmcnt(4)");
        } else {
            asm volatile("s_waitcnt vmcnt(0)");
        }
        __builtin_amdgcn_s_barrier();
        asm volatile("s_waitcnt lgkmcnt(0)");
        MFMA_TILE(av, bv1);
        __builtin_amdgcn_s_barrier();

        // phase C
        #pragma unroll
        for (int mi = 0; mi < 4; ++mi)
            av[mi] = *(const f16x8*)&bufc[8192 + arow + mi * 1024 + g0];
        if (stage) {
            GLOAD_LDS16(gAh + kn,       &bufn[loff]);
            GLOAD_LDS16(gAh + r64 + kn, &bufn[4096 + loff]);
        }
        __builtin_amdgcn_s_barrier();
        asm volatile("s_waitcnt lgkmcnt(0)");
        MFMA_TILE(av, bv0);
        __builtin_amdgcn_s_barrier();

        // phase D
        #pragma unroll
        for (int mi = 0; mi < 4; ++mi)
            av[mi] = *(const f16x8*)&bufc[8192 + arow + mi * 1024 + g1];
        if (stage) {
            GLOAD_LDS16(gAl + kn,       &bufn[ 8192 + loff]);
            GLOAD_LDS16(gAl + r64 + kn, &bufn[12288 + loff]);
        }
        asm volatile("s_waitcnt vmcnt(2)");
        __builtin_amdgcn_s_barrier();
        asm volatile("s_waitcnt lgkmcnt(0)");
        MFMA_TILE(av, bv1);
        __builtin_amdgcn_s_barrier();
    };

    for (int t = 0; t < nt - 1; ++t) tile_body(t, true);
    tile_body(nt - 1, false);

    #pragma unroll
    for (int mi = 0; mi < 4; ++mi) {
        #pragma unroll
        for (int ni = 0; ni < 4; ++ni) {
            #pragma unroll
            for (int rr = 0; rr < 4; ++rr) {
                const int row = row0 + wm * 64 + mi * 16 + lquad * 4 + rr;
                const int col = col0 + wn * 64 + ni * 16 + lrow;
                Cf[(size_t)row * N + col] = acc[mi][ni][rr];
            }
        }
    }
}

// ===========================================================================
// Split-K pass for the 16 half-dead diagonal jobs (by=2h, bx=h): live region
// is the 128x128 square at (row0=256h, col0=256h). grid = (8 kchunks, 16 jobs).
__global__ __launch_bounds__(256) void gemm_half_splitk(
    const f16* __restrict__ Ah, const f16* __restrict__ Al,
    const f16* __restrict__ B, float* __restrict__ Spart, int Kg)
{
    const int kc = blockIdx.x;       // 0..7
    const int h  = blockIdx.y;       // 0..15
    const int row0 = h * 256;        // == col0
    const int kbeg = kc * 256;

    const int tid   = threadIdx.x;
    const int lane  = tid & 63;
    const int wave  = tid >> 6;
    const int wm    = wave >> 1;
    const int wn    = wave & 1;
    const int lrow  = lane & 15;
    const int lquad = lane >> 4;

    __shared__ f16 sAh[BM * BK];
    __shared__ f16 sAl[BM * BK];
    __shared__ f16 sB [BM * BK];

    const int srow = tid >> 3;
    const int scol = (((tid & 7) ^ ((tid >> 3) & 7))) * 8;
    const int lbase = wave * 512;

    f32x4 acc[4][4];
    const f32x4 fz = {0.f, 0.f, 0.f, 0.f};
    #pragma unroll
    for (int i = 0; i < 4; ++i)
        #pragma unroll
        for (int jj = 0; jj < 4; ++jj) acc[i][jj] = fz;

    for (int k0 = kbeg; k0 < kbeg + 256; k0 += BK) {
        __syncthreads();
        #pragma unroll
        for (int r = 0; r < 4; ++r) {
            const int trow = srow + 32 * r;
            const size_t ga = (size_t)(row0 + trow) * Kg + k0 + scol;
            const int ldst = lbase + r * 2048;
            GLOAD_LDS16(&Ah[ga], &sAh[ldst]);
            GLOAD_LDS16(&Al[ga], &sAl[ldst]);
            GLOAD_LDS16(&B [ga], &sB [ldst]);   // B rows == A rows (diag)
        }
        __syncthreads();

        #pragma unroll
        for (int kk = 0; kk < 2; ++kk) {
            const int grpA = ((kk * 4 + lquad) ^ (lrow & 7)) * 8;
            f16x8 ah[4], al[4], bv[4];
            #pragma unroll
            for (int mi = 0; mi < 4; ++mi) {
                const int off = (wm * 64 + mi * 16 + lrow) * BK + grpA;
                ah[mi] = *reinterpret_cast<const f16x8*>(&sAh[off]);
                al[mi] = *reinterpret_cast<const f16x8*>(&sAl[off]);
            }
            #pragma unroll
            for (int ni = 0; ni < 4; ++ni)
                bv[ni] = *reinterpret_cast<const f16x8*>(
                    &sB[(wn * 64 + ni * 16 + lrow) * BK + grpA]);

            #pragma unroll
            for (int mi = 0; mi < 4; ++mi)
                #pragma unroll
                for (int ni = 0; ni < 4; ++ni) {
                    acc[mi][ni] = __builtin_amdgcn_mfma_f32_16x16x32_f16(
                        ah[mi], bv[ni], acc[mi][ni], 0, 0, 0);
                    acc[mi][ni] = __builtin_amdgcn_mfma_f32_16x16x32_f16(
                        al[mi], bv[ni], acc[mi][ni], 0, 0, 0);
                }
        }
    }

    float* outp = Spart + ((size_t)(kc * 16 + h)) * (128 * 128);
    #pragma unroll
    for (int mi = 0; mi < 4; ++mi) {
        #pragma unroll
        for (int ni = 0; ni < 4; ++ni) {
            #pragma unroll
            for (int r = 0; r < 4; ++r) {
                const int row = wm * 64 + mi * 16 + lquad * 4 + r;
                const int col = wn * 64 + ni * 16 + lrow;
                outp[row * 128 + col] = acc[mi][ni][r];
            }
        }
    }
}

// sum the 8 K-chunk partials of each half job into S. grid = (16, 16 jobs).
__global__ __launch_bounds__(256) void combine_halves(
    const float* __restrict__ Spart, float* __restrict__ S, int n)
{
    const int h = blockIdx.y;
    const int e = (blockIdx.x * 256 + threadIdx.x) * 4;   // 0..16383
    float4 a = *reinterpret_cast<const float4*>(
        &Spart[(size_t)h * (128 * 128) + e]);
    #pragma unroll
    for (int kc = 1; kc < 8; ++kc) {
        const float4 b = *reinterpret_cast<const float4*>(
            &Spart[(size_t)(kc * 16 + h) * (128 * 128) + e]);
        a.x += b.x; a.y += b.y; a.z += b.z; a.w += b.w;
    }
    const int i = e >> 7, jj = e & 127;
    *reinterpret_cast<float4*>(&S[(size_t)(h * 256 + i) * n + h * 256 + jj]) = a;
}

// ===========================================================================
// Pipelined single-term GEMM: C = A @ B^T, TRIPLE-buffered LDS (144 KiB).
// 2 phases/K-tile, 16 MFMA each; staging 2 tiles ahead; vmcnt(6) steady.
// KCAUSAL: K limited to (by+1)*128 (A=P rows are zero-padded to exactly that
// boundary by softmax); K param stays the row stride. Grid 256 = 1 block/CU
// (144 KiB LDS forces it), so makespan = the K=4096 row-block, no
// quantization. EPI: 0 = fp32 store, 2 = f16 store.
template <int EPI, bool KCAUSAL>
__global__ __launch_bounds__(512, 2) void gemm8_1t(
    const f16* __restrict__ A, const f16* __restrict__ B,
    float* __restrict__ Cf, f16* __restrict__ Co,
    int M, int N, int K)
{
    const int bx = blockIdx.x;
    const int by = KCAUSAL ? ((int)gridDim.y - 1 - (int)blockIdx.y) : blockIdx.y;

    const int tid   = threadIdx.x;
    const int lane  = tid & 63;
    const int wave  = tid >> 6;
    const int wm    = wave >> 2;
    const int wn    = wave & 3;
    const int lrow  = lane & 15;
    const int lquad = lane >> 4;

    __shared__ f16 lds[3][24576];   // 144 KiB total

    const int row0 = by * 128;
    const int col0 = bx * 256;

    const int srow = tid >> 3;
    const int scol = ((tid & 7) ^ (srow & 7)) * 8;
    const int loff = wave * 512;
    const int g0 = ((lquad)     ^ (lrow & 7)) * 8;
    const int g1 = ((4 + lquad) ^ (lrow & 7)) * 8;
    const int arow = (wm * 64 + lrow) * 64;
    const int brow = (wn * 64 + lrow) * 64 + 8192;

    const f16* gA = A + (size_t)(row0 + srow) * K + scol;
    const f16* gB = B + (size_t)(col0 + srow) * K + scol;
    const size_t r64 = (size_t)64 * K;

    f32x4 acc[4][4];
    const f32x4 fz = {0.f, 0.f, 0.f, 0.f};
    #pragma unroll
    for (int i = 0; i < 4; ++i)
        #pragma unroll
        for (int j = 0; j < 4; ++j) acc[i][j] = fz;

    const int Keff = KCAUSAL ? (by + 1) * 128 : K;
    const int nt = Keff / 64;   // >= 2 always (by=0 -> 2)

    // prologue: stage tiles 0 and 1 (order per tile: B0 B1 B2 B3 A0 A1)
    #pragma unroll
    for (int tt = 0; tt < 2; ++tt) {
        const size_t kk = (size_t)tt * 64;
        #pragma unroll
        for (int u = 0; u < 4; ++u)
            GLOAD_LDS16(gB + u * r64 + kk, &lds[tt][8192 + u * 4096 + loff]);
        #pragma unroll
        for (int u = 0; u < 2; ++u)
            GLOAD_LDS16(gA + u * r64 + kk, &lds[tt][u * 4096 + loff]);
    }
    asm volatile("s_waitcnt vmcnt(6)");   // tile 0 landed; tile 1 may fly
    __builtin_amdgcn_s_barrier();

    int cur = 0;
    for (int t = 0; t < nt; ++t) {
        const int nb = (cur >= 1) ? (cur - 1) : (cur + 2);  // (t+2) % 3
        const bool stage2 = (t + 2 < nt);
        const size_t kn = (size_t)(t + 2) * 64;
        const f16* bufc = &lds[cur][0];
        f16* bufn = &lds[nb][0];

        f16x8 av[4], bv[4];

        // ---------- phase A: kk0
        #pragma unroll
        for (int mi = 0; mi < 4; ++mi)
            av[mi] = *(const f16x8*)&bufc[arow + mi * 1024 + g0];
        #pragma unroll
        for (int ni = 0; ni < 4; ++ni)
            bv[ni] = *(const f16x8*)&bufc[brow + ni * 1024 + g0];
        if (stage2) {
            GLOAD_LDS16(gB + kn,           &bufn[8192 + loff]);
            GLOAD_LDS16(gB + r64 + kn,     &bufn[8192 + 4096 + loff]);
            GLOAD_LDS16(gB + 2 * r64 + kn, &bufn[8192 + 8192 + loff]);
        }
        __builtin_amdgcn_s_barrier();
        asm volatile("s_waitcnt lgkmcnt(0)");
        MFMA_TILE(av, bv);
        __builtin_amdgcn_s_barrier();

        // ---------- phase B: kk1
        #pragma unroll
        for (int mi = 0; mi < 4; ++mi)
            av[mi] = *(const f16x8*)&bufc[arow + mi * 1024 + g1];
        #pragma unroll
        for (int ni = 0; ni < 4; ++ni)
            bv[ni] = *(const f16x8*)&bufc[brow + ni * 1024 + g1];
        if (stage2) {
            GLOAD_LDS16(gB + 3 * r64 + kn, &bufn[8192 + 12288 + loff]);
            GLOAD_LDS16(gA + kn,           &bufn[loff]);
            GLOAD_LDS16(gA + r64 + kn,     &bufn[4096 + loff]);
            asm volatile("s_waitcnt vmcnt(6)");   // drain tile t+1
        } else {
            asm volatile("s_waitcnt vmcnt(0)");   // pipeline tail drain
        }
        __builtin_amdgcn_s_barrier();
        asm volatile("s_waitcnt lgkmcnt(0)");
        MFMA_TILE(av, bv);
        __builtin_amdgcn_s_barrier();

        cur = (cur == 2) ? 0 : cur + 1;
    }

    #pragma unroll
    for (int mi = 0; mi < 4; ++mi) {
        #pragma unroll
        for (int ni = 0; ni < 4; ++ni) {
            #pragma unroll
            for (int r = 0; r < 4; ++r) {
                const int row = row0 + wm * 64 + mi * 16 + lquad * 4 + r;
                const int col = col0 + wn * 64 + ni * 16 + lrow;
                const size_t idx = (size_t)row * N + col;
                const float v = acc[mi][ni][r];
                if (EPI == 0) Cf[idx] = v;
                else          Co[idx] = (f16)v;
            }
        }
    }
}

// fp32 -> f16 hi (+ optional lo residual), 4 elems/thread
__global__ __launch_bounds__(256) void split_f32_f16(
    const float* __restrict__ in, f16* __restrict__ hi, f16* __restrict__ lo,
    size_t nelem)
{
    const size_t i = ((size_t)blockIdx.x * 256 + threadIdx.x) * 4;
    if (i >= nelem) return;
    const float4 v = *reinterpret_cast<const float4*>(in + i);
    union { f16 h[4]; ushort4 u; } H, L;
    H.h[0] = (f16)v.x; H.h[1] = (f16)v.y; H.h[2] = (f16)v.z; H.h[3] = (f16)v.w;
    *reinterpret_cast<ushort4*>(hi + i) = H.u;
    if (lo) {
        L.h[0] = (f16)(v.x - (float)H.h[0]);
        L.h[1] = (f16)(v.y - (float)H.h[1]);
        L.h[2] = (f16)(v.z - (float)H.h[2]);
        L.h[3] = (f16)(v.w - (float)H.h[3]);
        *reinterpret_cast<ushort4*>(lo + i) = L.u;
    }
}

// fused: x -> xh (f16 hi), xl (f16 residual), xTh (f16 transpose).
// Reads x exactly once. 32x32 tiles, 256 thr.
__global__ __launch_bounds__(256) void prep_x(
    const float* __restrict__ in, f16* __restrict__ hi, f16* __restrict__ lo,
    f16* __restrict__ tr, int rows, int cols)
{
    __shared__ float tile[32][33];
    const int bx = blockIdx.x;
    const int by = blockIdx.y;
    const int tx = threadIdx.x & 31;
    const int ty = threadIdx.x >> 5;
    #pragma unroll
    for (int r = 0; r < 4; ++r) {
        const int row = by * 32 + ty + 8 * r;
        const int col = bx * 32 + tx;
        const float v = in[(size_t)row * cols + col];
        tile[ty + 8 * r][tx] = v;
        const f16 h = (f16)v;
        hi[(size_t)row * cols + col] = h;
        lo[(size_t)row * cols + col] = (f16)(v - (float)h);
    }
    __syncthreads();
    #pragma unroll
    for (int r = 0; r < 4; ++r)
        tr[(size_t)(bx * 32 + ty + 8 * r) * rows + by * 32 + tx] =
            (f16)tile[tx][ty + 8 * r];
}

// row-wise causal softmax, single global pass (row cached in LDS),
// online max+sum; zero-pads P to the 128 boundary.
__global__ __launch_bounds__(256) void softmax_rows(
    const float* __restrict__ S, f16* __restrict__ P, int n)
{
    const int row = blockIdx.x;
    const int len = row + 1;
    const int padlen = ((row >> 7) + 1) << 7;
    const float* srow = S + (size_t)row * n;
    f16* prow = P + (size_t)row * n;
    const int tid = threadIdx.x;
    const int lane = tid & 63, wave = tid >> 6;
    __shared__ float rowbuf[4096];   // 16 KB row cache (n <= 4096)
    __shared__ float redm[4], reds[4];

    float m = -3.0e38f, s = 0.f;
    for (int j = tid; j < len; j += 256) {
        const float v = srow[j];
        rowbuf[j] = v;
        const float mn = fmaxf(m, v);
        s = s * __expf(m - mn) + __expf(v - mn);
        m = mn;
    }
    #pragma unroll
    for (int off = 32; off; off >>= 1) {
        const float mo = __shfl_xor(m, off, 64);
        const float so = __shfl_xor(s, off, 64);
        const float mn = fmaxf(m, mo);
        s = s * __expf(m - mn) + so * __expf(mo - mn);
        m = mn;
    }
    if (lane == 0) { redm[wave] = m; reds[wave] = s; }
    __syncthreads();
    float M = redm[0], Sm = reds[0];
    #pragma unroll
    for (int w = 1; w < 4; ++w) {
        const float mn = fmaxf(M, redm[w]);
        Sm = Sm * __expf(M - mn) + reds[w] * __expf(redm[w] - mn);
        M = mn;
    }
    const float inv = 1.0f / Sm;

    const f16 z = (f16)0.0f;
    for (int j = tid; j < padlen; j += 256)
        prow[j] = (j < len) ? (f16)(__expf(rowbuf[j] - M) * inv) : z;
}

extern "C" void kernel_launch(void* const* d_in, const int* in_sizes, int n_in,
                              void* d_out, int out_size, void* d_ws, size_t ws_size,
                              hipStream_t stream)
{
    const int n = 4096, d = 2048;
    const float* x   = (const float*)d_in[0];
    const float* Wqk = (const float*)d_in[1];
    const float* Wov = (const float*)d_in[2];
    float* out = (float*)d_out;

    char* ws = (char*)d_ws;
    const size_t MB = 1 << 20;
    f16*   xh   = (f16*)  (ws);             // 16 MB  (n x d)
    f16*   xl   = (f16*)  (ws + 16 * MB);   // 16 MB  (dead after q GEMM)
    f16*   Wh   = (f16*)  (ws + 32 * MB);   //  8 MB  (d x d, dead after q GEMM)
    f16*   Wovh = (f16*)  (ws + 40 * MB);   //  8 MB  (live to end)
    f16*   xTh  = (f16*)  (ws + 48 * MB);   // 16 MB  (d x n, live to o GEMM)
    f16*   qh   = (f16*)  (ws + 64 * MB);   // 16 MB  (dead after S GEMM)
    f16*   ql   = (f16*)  (ws + 80 * MB);   // 16 MB  (dead after S GEMM)
    float* S    = (float*)(ws + 96 * MB);   // 64 MB  (n x n)  -> peak 160 MB
    float* Sp   = (float*)(ws + 16 * MB);   //  8 MB  split-K partials (over xl,
                                            //        dead; freed before P)
    f16*   P    = (f16*)  (ws);             // 32 MB  (n x n), over xh+xl (dead)
    f16*   o    = (f16*)  (ws + 64 * MB);   // 16 MB  (n x d), over qh (dead)

    const dim3 blk(256);
    const dim3 blk8(512);

    // fp32 -> f16 conversions (x split+transpose fused, reads x once)
    split_f32_f16<<<dim3((d * d) / (256 * 4)), blk, 0, stream>>>(Wqk, Wh, nullptr, (size_t)d * d);
    split_f32_f16<<<dim3((d * d) / (256 * 4)), blk, 0, stream>>>(Wov, Wovh, nullptr, (size_t)d * d);
    prep_x<<<dim3(d / 32, n / 32), blk, 0, stream>>>(x, xh, xl, xTh, n, d);

    // q = (xh+xl) @ Wh^T, pipelined 2-term, output split f16 hi/lo
    gemm8_a2<1><<<dim3(d / 256, n / 128), blk8, 0, stream>>>(
        xh, xl, Wh, nullptr, qh, ql, n, d, d);

    // S: 256 fully-live causal jobs, 1 block/CU, perfectly balanced
    gemm8_s_jobs<<<dim3(256), blk8, 0, stream>>>(qh, ql, xh, S, n, d);
    // 16 half-dead diagonal jobs, split-K 8-way, then combine into S
    gemm_half_splitk<<<dim3(8, 16), blk, 0, stream>>>(qh, ql, xh, Sp, d);
    combine_halves<<<dim3(16, 16), blk, 0, stream>>>(Sp, S, n);

    // P = causal row softmax(S), f16, zero-padded to 128 boundary
    softmax_rows<<<dim3(n), blk, 0, stream>>>(S, P, n);

    // o = P @ xTh^T, K causally limited per row-block; 8-phase pipelined,
    // 256 blocks = 1/CU, heavy rows dispatched first. K param = stride (n).
    gemm8_1t<2, true><<<dim3(d / 256, n / 128), blk8, 0, stream>>>(
        P, xTh, nullptr, o, n, d, n);

    // out = o @ Wovh^T, pipelined single-term, fp32 store to d_out
    gemm8_1t<0, false><<<dim3(d / 256, n / 128), blk8, 0, stream>>>(
        o, Wovh, out, nullptr, n, d, d);
}

// Round 6
// 365.851 us; speedup vs baseline: 1.2050x; 1.0398x over previous
//
#include <hip/hip_runtime.h>
#include <hip/hip_bf16.h>
#include <stdint.h>
#include <stddef.h>
#include <math.h>

typedef _Float16 f16;
typedef __attribute__((ext_vector_type(8))) _Float16 f16x8;  // 4 VGPRs (MFMA A/B)
typedef __attribute__((ext_vector_type(4))) float    f32x4;  // MFMA C/D

constexpr int BM = 128, BN = 128, BK = 64;   // half-splitk tiles

// async global->LDS DMA, 16 B/lane; LDS dest = wave-uniform base + lane*16
#define GLOAD_LDS16(gp, lp)                                        \
    __builtin_amdgcn_global_load_lds(                              \
        (const __attribute__((address_space(1))) unsigned int*)(gp),\
        (__attribute__((address_space(3))) unsigned int*)(lp), 16, 0, 0)

// one MFMA cluster: 16 x mfma_f32_16x16x32_f16 wrapped in setprio (T5)
#define MFMA_TILE(AV, BV)                                                     \
    do {                                                                      \
        __builtin_amdgcn_s_setprio(1);                                        \
        _Pragma("unroll")                                                     \
        for (int mi_ = 0; mi_ < 4; ++mi_)                                     \
            _Pragma("unroll")                                                 \
            for (int ni_ = 0; ni_ < 4; ++ni_)                                 \
                acc[mi_][ni_] = __builtin_amdgcn_mfma_f32_16x16x32_f16(       \
                    (AV)[mi_], (BV)[ni_], acc[mi_][ni_], 0, 0, 0);            \
        __builtin_amdgcn_s_setprio(0);                                        \
    } while (0)

// ===========================================================================
// Pipelined 2-term GEMM: C = (Ah+Al) @ B^T, f16 in / fp32 accum.
// BM=128, BN=256, BK=64, 512 threads = 8 waves (2M x 4N), 64x64 out/wave.
// LDS 128 KiB double-buffered: per buffer [Ah 16K][Al 16K][B 32K] bytes.
//
// SINGLE-BARRIER K-tile schedule (round-4 restructure): the old 4-phase /
// 8-barrier loop serialized the LDS-read drain (~2816 cyc/CU/tile) with the
// MFMA burst (~2480 cyc) -> measured 5400 cyc/tile = the serial sum. Now all
// 24 fragment ds_reads issue up front, the 8 next-tile DMAs follow (full-tile
// latency cover), 4 MFMA clusters consume fragments under compiler-staggered
// lgkmcnt, then ONE vmcnt(0)+barrier. Hazards: every read is consumed by an
// MFMA before the barrier (DS in-order; waits precede barrier), and per-wave
// vmcnt(0) precedes the barrier so all waves' DMA slices are visible.
template <int EPI>
__global__ __launch_bounds__(512, 2) void gemm8_a2(
    const f16* __restrict__ Ah, const f16* __restrict__ Al,
    const f16* __restrict__ B,
    float* __restrict__ Cf, f16* __restrict__ Co, f16* __restrict__ Clo,
    int M, int N, int K)
{
    const int bx = blockIdx.x;
    const int by = blockIdx.y;

    const int tid   = threadIdx.x;
    const int lane  = tid & 63;
    const int wave  = tid >> 6;   // 0..7
    const int wm    = wave >> 2;  // 0..1  (M)
    const int wn    = wave & 3;   // 0..3  (N)
    const int lrow  = lane & 15;
    const int lquad = lane >> 4;

    __shared__ f16 lds[2][32768];   // 128 KiB total

    const int row0 = by * 128;
    const int col0 = bx * 256;

    const int srow = tid >> 3;                       // 0..63 (row within unit)
    const int scol = ((tid & 7) ^ (srow & 7)) * 8;   // pre-swizzled source col
    const int loff = wave * 512;                     // wave slice inside a unit

    const int g0 = ((lquad)     ^ (lrow & 7)) * 8;   // swizzled group, kk=0
    const int g1 = ((4 + lquad) ^ (lrow & 7)) * 8;   // swizzled group, kk=1

    const int arow = (wm * 64 + lrow) * 64;           // A frag base (elems)
    const int brow = (wn * 64 + lrow) * 64 + 16384;   // B frag base (elems)

    const f16* gAh = Ah + (size_t)(row0 + srow) * K + scol;
    const f16* gAl = Al + (size_t)(row0 + srow) * K + scol;
    const f16* gB  = B  + (size_t)(col0 + srow) * K + scol;
    const size_t r64 = (size_t)64 * K;

    f32x4 acc[4][4];
    const f32x4 fz = {0.f, 0.f, 0.f, 0.f};
    #pragma unroll
    for (int i = 0; i < 4; ++i)
        #pragma unroll
        for (int j = 0; j < 4; ++j) acc[i][j] = fz;

    const int nt = K / 64;

    // prologue: stage tile 0 into buffer 0
    #pragma unroll
    for (int u = 0; u < 4; ++u)
        GLOAD_LDS16(gB + u * r64, &lds[0][16384 + u * 4096 + loff]);
    #pragma unroll
    for (int u = 0; u < 2; ++u)
        GLOAD_LDS16(gAh + u * r64, &lds[0][u * 4096 + loff]);
    #pragma unroll
    for (int u = 0; u < 2; ++u)
        GLOAD_LDS16(gAl + u * r64, &lds[0][8192 + u * 4096 + loff]);
    asm volatile("s_waitcnt vmcnt(0)");
    __builtin_amdgcn_s_barrier();

    for (int t = 0; t < nt; ++t) {
        const f16* bufc = &lds[t & 1][0];
        f16* bufn = &lds[(t + 1) & 1][0];
        const bool stage = (t + 1 < nt);
        const size_t kn = (size_t)(t + 1) * 64;

        f16x8 ah0[4], ah1[4], al0[4], al1[4], bv0[4], bv1[4];

        // issue ALL fragment reads for this K-tile (cluster order)
        #pragma unroll
        for (int mi = 0; mi < 4; ++mi)
            ah0[mi] = *(const f16x8*)&bufc[arow + mi * 1024 + g0];
        #pragma unroll
        for (int ni = 0; ni < 4; ++ni)
            bv0[ni] = *(const f16x8*)&bufc[brow + ni * 1024 + g0];
        #pragma unroll
        for (int mi = 0; mi < 4; ++mi)
            ah1[mi] = *(const f16x8*)&bufc[arow + mi * 1024 + g1];
        #pragma unroll
        for (int ni = 0; ni < 4; ++ni)
            bv1[ni] = *(const f16x8*)&bufc[brow + ni * 1024 + g1];
        #pragma unroll
        for (int mi = 0; mi < 4; ++mi)
            al0[mi] = *(const f16x8*)&bufc[8192 + arow + mi * 1024 + g0];
        #pragma unroll
        for (int mi = 0; mi < 4; ++mi)
            al1[mi] = *(const f16x8*)&bufc[8192 + arow + mi * 1024 + g1];

        // stage next tile (full-tile latency cover to the end-of-tile drain)
        if (stage) {
            GLOAD_LDS16(gB + kn,           &bufn[16384 + loff]);
            GLOAD_LDS16(gB + r64 + kn,     &bufn[16384 +  4096 + loff]);
            GLOAD_LDS16(gB + 2 * r64 + kn, &bufn[16384 +  8192 + loff]);
            GLOAD_LDS16(gB + 3 * r64 + kn, &bufn[16384 + 12288 + loff]);
            GLOAD_LDS16(gAh + kn,          &bufn[loff]);
            GLOAD_LDS16(gAh + r64 + kn,    &bufn[4096 + loff]);
            GLOAD_LDS16(gAl + kn,          &bufn[ 8192 + loff]);
            GLOAD_LDS16(gAl + r64 + kn,    &bufn[12288 + loff]);
        }

        MFMA_TILE(ah0, bv0);
        MFMA_TILE(ah1, bv1);
        MFMA_TILE(al0, bv0);
        MFMA_TILE(al1, bv1);

        asm volatile("s_waitcnt vmcnt(0)");   // next-tile DMA landed (own wave)
        __builtin_amdgcn_s_barrier();          // all waves: reads done + DMA seen
    }

    // epilogue: D element (row = lquad*4 + r, col = lrow) within 16x16 tiles
    #pragma unroll
    for (int mi = 0; mi < 4; ++mi) {
        #pragma unroll
        for (int ni = 0; ni < 4; ++ni) {
            #pragma unroll
            for (int r = 0; r < 4; ++r) {
                const int row = row0 + wm * 64 + mi * 16 + lquad * 4 + r;
                const int col = col0 + wn * 64 + ni * 16 + lrow;
                const size_t idx = (size_t)row * N + col;
                const float v = acc[mi][ni][r];
                if (EPI == 0) {
                    Cf[idx] = v;
                } else {
                    const f16 h = (f16)v;
                    Co[idx]  = h;
                    Clo[idx] = (f16)(v - (float)h);
                }
            }
        }
    }
}

// ===========================================================================
// S-GEMM main dispatch: the 256 FULLY-LIVE causal jobs, one block each,
// perfectly balanced 1 block/CU. Job map: r = floor(sqrt(j)); u = j - r^2;
// (by,bx) = u<r ? (2r, u) : (2r+1, u-r). XCD remap b -> j = (b&7)*32 + (b>>3).
// Same single-barrier K-tile schedule as gemm8_a2.
__global__ __launch_bounds__(512, 2) void gemm8_s_jobs(
    const f16* __restrict__ Ah, const f16* __restrict__ Al,
    const f16* __restrict__ B,
    float* __restrict__ Cf, int N, int K)
{
    const int b = blockIdx.x;
    const int j = (b & 7) * 32 + (b >> 3);
    int r = (int)sqrtf((float)j);
    while (r * r > j) --r;
    while ((r + 1) * (r + 1) <= j) ++r;
    const int u = j - r * r;
    const int by = (u < r) ? 2 * r : 2 * r + 1;
    const int bx = (u < r) ? u : u - r;

    const int tid   = threadIdx.x;
    const int lane  = tid & 63;
    const int wave  = tid >> 6;
    const int wm    = wave >> 2;
    const int wn    = wave & 3;
    const int lrow  = lane & 15;
    const int lquad = lane >> 4;

    __shared__ f16 lds[2][32768];   // 128 KiB

    const int row0 = by * 128;
    const int col0 = bx * 256;

    const int srow = tid >> 3;
    const int scol = ((tid & 7) ^ (srow & 7)) * 8;
    const int loff = wave * 512;

    const int g0 = ((lquad)     ^ (lrow & 7)) * 8;
    const int g1 = ((4 + lquad) ^ (lrow & 7)) * 8;

    const int arow = (wm * 64 + lrow) * 64;
    const int brow = (wn * 64 + lrow) * 64 + 16384;

    const f16* gAh = Ah + (size_t)(row0 + srow) * K + scol;
    const f16* gAl = Al + (size_t)(row0 + srow) * K + scol;
    const f16* gB  = B  + (size_t)(col0 + srow) * K + scol;
    const size_t r64 = (size_t)64 * K;

    f32x4 acc[4][4];
    const f32x4 fz = {0.f, 0.f, 0.f, 0.f};
    #pragma unroll
    for (int i = 0; i < 4; ++i)
        #pragma unroll
        for (int jj = 0; jj < 4; ++jj) acc[i][jj] = fz;

    const int nt = K / 64;

    #pragma unroll
    for (int u2 = 0; u2 < 4; ++u2)
        GLOAD_LDS16(gB + u2 * r64, &lds[0][16384 + u2 * 4096 + loff]);
    #pragma unroll
    for (int u2 = 0; u2 < 2; ++u2)
        GLOAD_LDS16(gAh + u2 * r64, &lds[0][u2 * 4096 + loff]);
    #pragma unroll
    for (int u2 = 0; u2 < 2; ++u2)
        GLOAD_LDS16(gAl + u2 * r64, &lds[0][8192 + u2 * 4096 + loff]);
    asm volatile("s_waitcnt vmcnt(0)");
    __builtin_amdgcn_s_barrier();

    for (int t = 0; t < nt; ++t) {
        const f16* bufc = &lds[t & 1][0];
        f16* bufn = &lds[(t + 1) & 1][0];
        const bool stage = (t + 1 < nt);
        const size_t kn = (size_t)(t + 1) * 64;

        f16x8 ah0[4], ah1[4], al0[4], al1[4], bv0[4], bv1[4];

        #pragma unroll
        for (int mi = 0; mi < 4; ++mi)
            ah0[mi] = *(const f16x8*)&bufc[arow + mi * 1024 + g0];
        #pragma unroll
        for (int ni = 0; ni < 4; ++ni)
            bv0[ni] = *(const f16x8*)&bufc[brow + ni * 1024 + g0];
        #pragma unroll
        for (int mi = 0; mi < 4; ++mi)
            ah1[mi] = *(const f16x8*)&bufc[arow + mi * 1024 + g1];
        #pragma unroll
        for (int ni = 0; ni < 4; ++ni)
            bv1[ni] = *(const f16x8*)&bufc[brow + ni * 1024 + g1];
        #pragma unroll
        for (int mi = 0; mi < 4; ++mi)
            al0[mi] = *(const f16x8*)&bufc[8192 + arow + mi * 1024 + g0];
        #pragma unroll
        for (int mi = 0; mi < 4; ++mi)
            al1[mi] = *(const f16x8*)&bufc[8192 + arow + mi * 1024 + g1];

        if (stage) {
            GLOAD_LDS16(gB + kn,           &bufn[16384 + loff]);
            GLOAD_LDS16(gB + r64 + kn,     &bufn[16384 +  4096 + loff]);
            GLOAD_LDS16(gB + 2 * r64 + kn, &bufn[16384 +  8192 + loff]);
            GLOAD_LDS16(gB + 3 * r64 + kn, &bufn[16384 + 12288 + loff]);
            GLOAD_LDS16(gAh + kn,          &bufn[loff]);
            GLOAD_LDS16(gAh + r64 + kn,    &bufn[4096 + loff]);
            GLOAD_LDS16(gAl + kn,          &bufn[ 8192 + loff]);
            GLOAD_LDS16(gAl + r64 + kn,    &bufn[12288 + loff]);
        }

        MFMA_TILE(ah0, bv0);
        MFMA_TILE(ah1, bv1);
        MFMA_TILE(al0, bv0);
        MFMA_TILE(al1, bv1);

        asm volatile("s_waitcnt vmcnt(0)");
        __builtin_amdgcn_s_barrier();
    }

    #pragma unroll
    for (int mi = 0; mi < 4; ++mi) {
        #pragma unroll
        for (int ni = 0; ni < 4; ++ni) {
            #pragma unroll
            for (int rr = 0; rr < 4; ++rr) {
                const int row = row0 + wm * 64 + mi * 16 + lquad * 4 + rr;
                const int col = col0 + wn * 64 + ni * 16 + lrow;
                Cf[(size_t)row * N + col] = acc[mi][ni][rr];
            }
        }
    }
}

// ===========================================================================
// Split-K pass for the 16 half-dead diagonal jobs (by=2h, bx=h): live region
// is the 128x128 square at (row0=256h, col0=256h). grid = (8 kchunks, 16 jobs).
__global__ __launch_bounds__(256) void gemm_half_splitk(
    const f16* __restrict__ Ah, const f16* __restrict__ Al,
    const f16* __restrict__ B, float* __restrict__ Spart, int Kg)
{
    const int kc = blockIdx.x;       // 0..7
    const int h  = blockIdx.y;       // 0..15
    const int row0 = h * 256;        // == col0
    const int kbeg = kc * 256;

    const int tid   = threadIdx.x;
    const int lane  = tid & 63;
    const int wave  = tid >> 6;
    const int wm    = wave >> 1;
    const int wn    = wave & 1;
    const int lrow  = lane & 15;
    const int lquad = lane >> 4;

    __shared__ f16 sAh[BM * BK];
    __shared__ f16 sAl[BM * BK];
    __shared__ f16 sB [BM * BK];

    const int srow = tid >> 3;
    const int scol = (((tid & 7) ^ ((tid >> 3) & 7))) * 8;
    const int lbase = wave * 512;

    f32x4 acc[4][4];
    const f32x4 fz = {0.f, 0.f, 0.f, 0.f};
    #pragma unroll
    for (int i = 0; i < 4; ++i)
        #pragma unroll
        for (int jj = 0; jj < 4; ++jj) acc[i][jj] = fz;

    for (int k0 = kbeg; k0 < kbeg + 256; k0 += BK) {
        __syncthreads();
        #pragma unroll
        for (int r = 0; r < 4; ++r) {
            const int trow = srow + 32 * r;
            const size_t ga = (size_t)(row0 + trow) * Kg + k0 + scol;
            const int ldst = lbase + r * 2048;
            GLOAD_LDS16(&Ah[ga], &sAh[ldst]);
            GLOAD_LDS16(&Al[ga], &sAl[ldst]);
            GLOAD_LDS16(&B [ga], &sB [ldst]);   // B rows == A rows (diag)
        }
        __syncthreads();

        #pragma unroll
        for (int kk = 0; kk < 2; ++kk) {
            const int grpA = ((kk * 4 + lquad) ^ (lrow & 7)) * 8;
            f16x8 ah[4], al[4], bv[4];
            #pragma unroll
            for (int mi = 0; mi < 4; ++mi) {
                const int off = (wm * 64 + mi * 16 + lrow) * BK + grpA;
                ah[mi] = *reinterpret_cast<const f16x8*>(&sAh[off]);
                al[mi] = *reinterpret_cast<const f16x8*>(&sAl[off]);
            }
            #pragma unroll
            for (int ni = 0; ni < 4; ++ni)
                bv[ni] = *reinterpret_cast<const f16x8*>(
                    &sB[(wn * 64 + ni * 16 + lrow) * BK + grpA]);

            #pragma unroll
            for (int mi = 0; mi < 4; ++mi)
                #pragma unroll
                for (int ni = 0; ni < 4; ++ni) {
                    acc[mi][ni] = __builtin_amdgcn_mfma_f32_16x16x32_f16(
                        ah[mi], bv[ni], acc[mi][ni], 0, 0, 0);
                    acc[mi][ni] = __builtin_amdgcn_mfma_f32_16x16x32_f16(
                        al[mi], bv[ni], acc[mi][ni], 0, 0, 0);
                }
        }
    }

    float* outp = Spart + ((size_t)(kc * 16 + h)) * (128 * 128);
    #pragma unroll
    for (int mi = 0; mi < 4; ++mi) {
        #pragma unroll
        for (int ni = 0; ni < 4; ++ni) {
            #pragma unroll
            for (int r = 0; r < 4; ++r) {
                const int row = wm * 64 + mi * 16 + lquad * 4 + r;
                const int col = wn * 64 + ni * 16 + lrow;
                outp[row * 128 + col] = acc[mi][ni][r];
            }
        }
    }
}

// sum the 8 K-chunk partials of each half job into S. grid = (16, 16 jobs).
__global__ __launch_bounds__(256) void combine_halves(
    const float* __restrict__ Spart, float* __restrict__ S, int n)
{
    const int h = blockIdx.y;
    const int e = (blockIdx.x * 256 + threadIdx.x) * 4;   // 0..16383
    float4 a = *reinterpret_cast<const float4*>(
        &Spart[(size_t)h * (128 * 128) + e]);
    #pragma unroll
    for (int kc = 1; kc < 8; ++kc) {
        const float4 b = *reinterpret_cast<const float4*>(
            &Spart[(size_t)(kc * 16 + h) * (128 * 128) + e]);
        a.x += b.x; a.y += b.y; a.z += b.z; a.w += b.w;
    }
    const int i = e >> 7, jj = e & 127;
    *reinterpret_cast<float4*>(&S[(size_t)(h * 256 + i) * n + h * 256 + jj]) = a;
}

// ===========================================================================
// Pipelined single-term GEMM: C = A @ B^T, TRIPLE-buffered LDS (144 KiB).
// Single-barrier K-tile schedule: 16 fragment reads up front, 6 DMAs (tile
// t+2) follow, 2 MFMA clusters, vmcnt(6) [2-tile cover], one barrier.
// KCAUSAL: K limited to (by+1)*128 (P rows zero-padded to that boundary).
// EPI: 0 = fp32 store, 2 = f16 store.
template <int EPI, bool KCAUSAL>
__global__ __launch_bounds__(512, 2) void gemm8_1t(
    const f16* __restrict__ A, const f16* __restrict__ B,
    float* __restrict__ Cf, f16* __restrict__ Co,
    int M, int N, int K)
{
    const int bx = blockIdx.x;
    const int by = KCAUSAL ? ((int)gridDim.y - 1 - (int)blockIdx.y) : blockIdx.y;

    const int tid   = threadIdx.x;
    const int lane  = tid & 63;
    const int wave  = tid >> 6;
    const int wm    = wave >> 2;
    const int wn    = wave & 3;
    const int lrow  = lane & 15;
    const int lquad = lane >> 4;

    __shared__ f16 lds[3][24576];   // 144 KiB total

    const int row0 = by * 128;
    const int col0 = bx * 256;

    const int srow = tid >> 3;
    const int scol = ((tid & 7) ^ (srow & 7)) * 8;
    const int loff = wave * 512;
    const int g0 = ((lquad)     ^ (lrow & 7)) * 8;
    const int g1 = ((4 + lquad) ^ (lrow & 7)) * 8;
    const int arow = (wm * 64 + lrow) * 64;
    const int brow = (wn * 64 + lrow) * 64 + 8192;

    const f16* gA = A + (size_t)(row0 + srow) * K + scol;
    const f16* gB = B + (size_t)(col0 + srow) * K + scol;
    const size_t r64 = (size_t)64 * K;

    f32x4 acc[4][4];
    const f32x4 fz = {0.f, 0.f, 0.f, 0.f};
    #pragma unroll
    for (int i = 0; i < 4; ++i)
        #pragma unroll
        for (int j = 0; j < 4; ++j) acc[i][j] = fz;

    const int Keff = KCAUSAL ? (by + 1) * 128 : K;
    const int nt = Keff / 64;   // >= 2 always (by=0 -> 2)

    // prologue: stage tiles 0 and 1 (order per tile: B0 B1 B2 B3 A0 A1)
    #pragma unroll
    for (int tt = 0; tt < 2; ++tt) {
        const size_t kk = (size_t)tt * 64;
        #pragma unroll
        for (int u = 0; u < 4; ++u)
            GLOAD_LDS16(gB + u * r64 + kk, &lds[tt][8192 + u * 4096 + loff]);
        #pragma unroll
        for (int u = 0; u < 2; ++u)
            GLOAD_LDS16(gA + u * r64 + kk, &lds[tt][u * 4096 + loff]);
    }
    asm volatile("s_waitcnt vmcnt(6)");   // tile 0 landed; tile 1 may fly
    __builtin_amdgcn_s_barrier();

    int cur = 0;
    for (int t = 0; t < nt; ++t) {
        const int nb = (cur >= 1) ? (cur - 1) : (cur + 2);  // (t+2) % 3
        const bool stage2 = (t + 2 < nt);
        const size_t kn = (size_t)(t + 2) * 64;
        const f16* bufc = &lds[cur][0];
        f16* bufn = &lds[nb][0];

        f16x8 av0[4], av1[4], bv0[4], bv1[4];

        #pragma unroll
        for (int mi = 0; mi < 4; ++mi)
            av0[mi] = *(const f16x8*)&bufc[arow + mi * 1024 + g0];
        #pragma unroll
        for (int ni = 0; ni < 4; ++ni)
            bv0[ni] = *(const f16x8*)&bufc[brow + ni * 1024 + g0];
        #pragma unroll
        for (int mi = 0; mi < 4; ++mi)
            av1[mi] = *(const f16x8*)&bufc[arow + mi * 1024 + g1];
        #pragma unroll
        for (int ni = 0; ni < 4; ++ni)
            bv1[ni] = *(const f16x8*)&bufc[brow + ni * 1024 + g1];

        if (stage2) {
            GLOAD_LDS16(gB + kn,           &bufn[8192 + loff]);
            GLOAD_LDS16(gB + r64 + kn,     &bufn[8192 +  4096 + loff]);
            GLOAD_LDS16(gB + 2 * r64 + kn, &bufn[8192 +  8192 + loff]);
            GLOAD_LDS16(gB + 3 * r64 + kn, &bufn[8192 + 12288 + loff]);
            GLOAD_LDS16(gA + kn,           &bufn[loff]);
            GLOAD_LDS16(gA + r64 + kn,     &bufn[4096 + loff]);
        }

        MFMA_TILE(av0, bv0);
        MFMA_TILE(av1, bv1);

        if (stage2) asm volatile("s_waitcnt vmcnt(6)");  // drain t-1 batch
        else        asm volatile("s_waitcnt vmcnt(0)");  // pipeline tail
        __builtin_amdgcn_s_barrier();

        cur = (cur == 2) ? 0 : cur + 1;
    }

    #pragma unroll
    for (int mi = 0; mi < 4; ++mi) {
        #pragma unroll
        for (int ni = 0; ni < 4; ++ni) {
            #pragma unroll
            for (int r = 0; r < 4; ++r) {
                const int row = row0 + wm * 64 + mi * 16 + lquad * 4 + r;
                const int col = col0 + wn * 64 + ni * 16 + lrow;
                const size_t idx = (size_t)row * N + col;
                const float v = acc[mi][ni][r];
                if (EPI == 0) Cf[idx] = v;
                else          Co[idx] = (f16)v;
            }
        }
    }
}

// fp32 -> f16 hi (+ optional lo residual), 4 elems/thread
__global__ __launch_bounds__(256) void split_f32_f16(
    const float* __restrict__ in, f16* __restrict__ hi, f16* __restrict__ lo,
    size_t nelem)
{
    const size_t i = ((size_t)blockIdx.x * 256 + threadIdx.x) * 4;
    if (i >= nelem) return;
    const float4 v = *reinterpret_cast<const float4*>(in + i);
    union { f16 h[4]; ushort4 u; } H, L;
    H.h[0] = (f16)v.x; H.h[1] = (f16)v.y; H.h[2] = (f16)v.z; H.h[3] = (f16)v.w;
    *reinterpret_cast<ushort4*>(hi + i) = H.u;
    if (lo) {
        L.h[0] = (f16)(v.x - (float)H.h[0]);
        L.h[1] = (f16)(v.y - (float)H.h[1]);
        L.h[2] = (f16)(v.z - (float)H.h[2]);
        L.h[3] = (f16)(v.w - (float)H.h[3]);
        *reinterpret_cast<ushort4*>(lo + i) = L.u;
    }
}

// fused: x -> xh (f16 hi), xl (f16 residual), xTh (f16 transpose).
// Reads x exactly once. 32x32 tiles, 256 thr.
__global__ __launch_bounds__(256) void prep_x(
    const float* __restrict__ in, f16* __restrict__ hi, f16* __restrict__ lo,
    f16* __restrict__ tr, int rows, int cols)
{
    __shared__ float tile[32][33];
    const int bx = blockIdx.x;
    const int by = blockIdx.y;
    const int tx = threadIdx.x & 31;
    const int ty = threadIdx.x >> 5;
    #pragma unroll
    for (int r = 0; r < 4; ++r) {
        const int row = by * 32 + ty + 8 * r;
        const int col = bx * 32 + tx;
        const float v = in[(size_t)row * cols + col];
        tile[ty + 8 * r][tx] = v;
        const f16 h = (f16)v;
        hi[(size_t)row * cols + col] = h;
        lo[(size_t)row * cols + col] = (f16)(v - (float)h);
    }
    __syncthreads();
    #pragma unroll
    for (int r = 0; r < 4; ++r)
        tr[(size_t)(bx * 32 + ty + 8 * r) * rows + by * 32 + tx] =
            (f16)tile[tx][ty + 8 * r];
}

// row-wise causal softmax, single global pass (row cached in LDS),
// online max+sum; zero-pads P to the 128 boundary.
__global__ __launch_bounds__(256) void softmax_rows(
    const float* __restrict__ S, f16* __restrict__ P, int n)
{
    const int row = blockIdx.x;
    const int len = row + 1;
    const int padlen = ((row >> 7) + 1) << 7;
    const float* srow = S + (size_t)row * n;
    f16* prow = P + (size_t)row * n;
    const int tid = threadIdx.x;
    const int lane = tid & 63, wave = tid >> 6;
    __shared__ float rowbuf[4096];   // 16 KB row cache (n <= 4096)
    __shared__ float redm[4], reds[4];

    float m = -3.0e38f, s = 0.f;
    for (int j = tid; j < len; j += 256) {
        const float v = srow[j];
        rowbuf[j] = v;
        const float mn = fmaxf(m, v);
        s = s * __expf(m - mn) + __expf(v - mn);
        m = mn;
    }
    #pragma unroll
    for (int off = 32; off; off >>= 1) {
        const float mo = __shfl_xor(m, off, 64);
        const float so = __shfl_xor(s, off, 64);
        const float mn = fmaxf(m, mo);
        s = s * __expf(m - mn) + so * __expf(mo - mn);
        m = mn;
    }
    if (lane == 0) { redm[wave] = m; reds[wave] = s; }
    __syncthreads();
    float M = redm[0], Sm = reds[0];
    #pragma unroll
    for (int w = 1; w < 4; ++w) {
        const float mn = fmaxf(M, redm[w]);
        Sm = Sm * __expf(M - mn) + reds[w] * __expf(redm[w] - mn);
        M = mn;
    }
    const float inv = 1.0f / Sm;

    const f16 z = (f16)0.0f;
    for (int j = tid; j < padlen; j += 256)
        prow[j] = (j < len) ? (f16)(__expf(rowbuf[j] - M) * inv) : z;
}

extern "C" void kernel_launch(void* const* d_in, const int* in_sizes, int n_in,
                              void* d_out, int out_size, void* d_ws, size_t ws_size,
                              hipStream_t stream)
{
    const int n = 4096, d = 2048;
    const float* x   = (const float*)d_in[0];
    const float* Wqk = (const float*)d_in[1];
    const float* Wov = (const float*)d_in[2];
    float* out = (float*)d_out;

    char* ws = (char*)d_ws;
    const size_t MB = 1 << 20;
    f16*   xh   = (f16*)  (ws);             // 16 MB  (n x d)
    f16*   xl   = (f16*)  (ws + 16 * MB);   // 16 MB  (dead after q GEMM)
    f16*   Wh   = (f16*)  (ws + 32 * MB);   //  8 MB  (d x d, dead after q GEMM)
    f16*   Wovh = (f16*)  (ws + 40 * MB);   //  8 MB  (live to end)
    f16*   xTh  = (f16*)  (ws + 48 * MB);   // 16 MB  (d x n, live to o GEMM)
    f16*   qh   = (f16*)  (ws + 64 * MB);   // 16 MB  (dead after S GEMM)
    f16*   ql   = (f16*)  (ws + 80 * MB);   // 16 MB  (dead after S GEMM)
    float* S    = (float*)(ws + 96 * MB);   // 64 MB  (n x n)  -> peak 160 MB
    float* Sp   = (float*)(ws + 16 * MB);   //  8 MB  split-K partials (over xl,
                                            //        dead; freed before P)
    f16*   P    = (f16*)  (ws);             // 32 MB  (n x n), over xh+xl (dead)
    f16*   o    = (f16*)  (ws + 64 * MB);   // 16 MB  (n x d), over qh (dead)

    const dim3 blk(256);
    const dim3 blk8(512);

    // fp32 -> f16 conversions (x split+transpose fused, reads x once)
    split_f32_f16<<<dim3((d * d) / (256 * 4)), blk, 0, stream>>>(Wqk, Wh, nullptr, (size_t)d * d);
    split_f32_f16<<<dim3((d * d) / (256 * 4)), blk, 0, stream>>>(Wov, Wovh, nullptr, (size_t)d * d);
    prep_x<<<dim3(d / 32, n / 32), blk, 0, stream>>>(x, xh, xl, xTh, n, d);

    // q = (xh+xl) @ Wh^T, pipelined 2-term, output split f16 hi/lo
    gemm8_a2<1><<<dim3(d / 256, n / 128), blk8, 0, stream>>>(
        xh, xl, Wh, nullptr, qh, ql, n, d, d);

    // S: 256 fully-live causal jobs, 1 block/CU, perfectly balanced
    gemm8_s_jobs<<<dim3(256), blk8, 0, stream>>>(qh, ql, xh, S, n, d);
    // 16 half-dead diagonal jobs, split-K 8-way, then combine into S
    gemm_half_splitk<<<dim3(8, 16), blk, 0, stream>>>(qh, ql, xh, Sp, d);
    combine_halves<<<dim3(16, 16), blk, 0, stream>>>(Sp, S, n);

    // P = causal row softmax(S), f16, zero-padded to 128 boundary
    softmax_rows<<<dim3(n), blk, 0, stream>>>(S, P, n);

    // o = P @ xTh^T, K causally limited per row-block; 256 blocks = 1/CU,
    // heavy rows dispatched first. K param = stride (n).
    gemm8_1t<2, true><<<dim3(d / 256, n / 128), blk8, 0, stream>>>(
        P, xTh, nullptr, o, n, d, n);

    // out = o @ Wovh^T, pipelined single-term, fp32 store to d_out
    gemm8_1t<0, false><<<dim3(d / 256, n / 128), blk8, 0, stream>>>(
        o, Wovh, out, nullptr, n, d, d);
}